// Round 10
// baseline (703.359 us; speedup 1.0000x reference)
//
#include <hip/hip_runtime.h>

typedef unsigned long long u64;
typedef unsigned short u16;
typedef unsigned int u32;

// ---------------------------------------------------------------------------
// HierarchicalLFQHVQVAE forward — R18.
// Base = R17 (667 us). R17 post-mortem: q-dist port -20us; top-5 = 5x z-dist
// at 109us. Cycle budget shows z-dist is LDS-PIPE-bound: bf reads 64KB/iter
// (2x redundancy: both code-half waves re-read every row) + 520cyc/iter bank
// conflicts + 510cyc DMA writes ~= 2.7K of the 4.1K cyc/iter.
// R18: dist3z — flip the wave decomposition to kill the redundancy:
//  - CT=32 codes x BR=128 rows; 4 waves each own 32 ROWS and compute ALL 32
//    codes (af[8][2]=64 VGPR hoist, total ~110 <= 128). Each row read by
//    exactly ONE wave -> LDS read traffic -50%, total LDS traffic -33%.
//  - per-row min over all 32 codes is wave-local: wred+merge phase DELETED
//    (2 shfl); cand stored from registers after the stage-DMA issue, so
//    vmcnt(2) drains the 16 loads and leaves the 2 stores in flight.
//  - LDS 16K(bufC)+64K(bufB)=80KB -> 2 blocks/CU = 160KB exact fit.
//  - ncand 64->128 tiles (recall strictly better). z-rerank: NC=128 via
//    8x wave-min-scan over 2 keys/lane (no LDS, no syncthreads — cheaper
//    than the rank loop; R11's scan was never the problem).
// q-dist (R17 dist2z), GEMMs, prep, finalize: unchanged.
// candz relocated to 0x5C80000 (16MB; inside the region hs already proved
// allocated; no temporal overlap with qqb/zqs).
// ---------------------------------------------------------------------------

namespace {

constexpr int kBatch = 32768;

__device__ __forceinline__ float gelu_f(float x) {
  return 0.5f * x * (1.0f + erff(x * 0.70710678118654752440f));
}
__device__ __forceinline__ float sigmoid_f(float x) {
  return 1.0f / (1.0f + expf(-x));
}
__device__ __forceinline__ u64 pack_key(float d, unsigned j) {
  unsigned u = __float_as_uint(d);
  u = (u & 0x80000000u) ? ~u : (u | 0x80000000u);
  return ((u64)u << 32) | j;
}
__device__ __forceinline__ u16 bf16_rne(float x) {
  unsigned u = __float_as_uint(x);
  unsigned r = (u + 0x7FFFu + ((u >> 16) & 1u)) >> 16;
  return (u16)r;
}
__device__ __forceinline__ float bf16_to_f(u16 h) {
  return __uint_as_float((unsigned)h << 16);
}
__device__ __forceinline__ u64 min64(u64 a, u64 b) { return a < b ? a : b; }

__device__ __forceinline__ void load_lds16(const void* g, void* l) {
  __builtin_amdgcn_global_load_lds(
      (const __attribute__((address_space(1))) void*)g,
      (__attribute__((address_space(3))) void*)l, 16, 0, 0);
}

template <int N>
__device__ __forceinline__ void wait_vmcnt() {
  if constexpr (N == 0) {
    asm volatile("s_waitcnt vmcnt(0)" ::: "memory");
  } else if constexpr (N == 1) {
    asm volatile("s_waitcnt vmcnt(1)" ::: "memory");
  } else if constexpr (N == 2) {
    asm volatile("s_waitcnt vmcnt(2)" ::: "memory");
  } else if constexpr (N == 8) {
    asm volatile("s_waitcnt vmcnt(8)" ::: "memory");
  } else if constexpr (N == 16) {
    asm volatile("s_waitcnt vmcnt(16)" ::: "memory");
  }
}

__device__ __forceinline__ void lds_fence_barrier_pre() {
  // order: all prior LDS ops retired, then barrier
  asm volatile("s_waitcnt lgkmcnt(0)" ::: "memory");
  __builtin_amdgcn_sched_barrier(0);
  __builtin_amdgcn_s_barrier();
  asm volatile("" ::: "memory");  // no LDS op hoists above the barrier
  __builtin_amdgcn_sched_barrier(0);
}

__device__ __forceinline__ void barrier_raw() {
  __builtin_amdgcn_sched_barrier(0);
  __builtin_amdgcn_s_barrier();
  asm volatile("" ::: "memory");  // no LDS op hoists above the barrier
  __builtin_amdgcn_sched_barrier(0);
}

typedef short bf16x8 __attribute__((ext_vector_type(8)));
typedef float f32x4 __attribute__((ext_vector_type(4)));

// ===========================================================================
// Prep (3 kernels) — identical to R6
// ===========================================================================
__global__ void prep_cb_kernel(const float* __restrict__ zcb,
                               u16* __restrict__ zcbh, float* __restrict__ zcbn,
                               const float* __restrict__ qcb,
                               u16* __restrict__ qcbh, float* __restrict__ qcbn) {
  int b = blockIdx.x;
  const float* cb;
  u16* cbh;
  float* cbn;
  int K;
  if (b < 1024) { cb = zcb; cbh = zcbh; cbn = zcbn; K = 256; }
  else { b -= 1024; cb = qcb; cbh = qcbh; cbn = qcbn; K = 128; }
  const int row = b * 4 + (threadIdx.x >> 6);
  const int lane = threadIdx.x & 63;
  double s = 0.0;
  for (int k = lane; k < K; k += 64) {
    const float v = cb[(size_t)row * K + k];
    cbh[(size_t)row * K + k] = bf16_rne(v);
    s += (double)v * (double)v;
  }
#pragma unroll
  for (int o = 32; o > 0; o >>= 1) s += __shfl_down(s, o);
  if (lane == 0) cbn[row] = (float)s;
}

__global__ void prep_w_kernel(
    const float* __restrict__ zW, const float* __restrict__ zci,
    const float* __restrict__ qW, const float* __restrict__ qci,
    const float* __restrict__ eW1, const float* __restrict__ eW2,
    u16* __restrict__ zWns, u16* __restrict__ qWns, u16* __restrict__ eW1s,
    u16* __restrict__ eW2s, const float* __restrict__ dW1,
    const float* __restrict__ dW2, const float* __restrict__ oW,
    u16* __restrict__ dW1b, u16* __restrict__ dW2b, u16* __restrict__ oWb) {
  const int b = blockIdx.x;
  const int tid = threadIdx.x;
  if (b < 384) {
    const float* W;
    const float* ci;
    u16* D;
    int K, row;
    if (b < 256) { W = zW; ci = zci; D = zWns; K = 512; row = b; }
    else { W = qW; ci = qci; D = qWns; K = 256; row = b - 256; }
    float s = 0.f;
    for (int k = tid; k < K; k += 256) s += fabsf(W[(size_t)row * K + k]);
#pragma unroll
    for (int o = 32; o > 0; o >>= 1) s += __shfl_down(s, o);
    __shared__ float p[4];
    if ((tid & 63) == 0) p[tid >> 6] = s;
    __syncthreads();
    const float tot = p[0] + p[1] + p[2] + p[3];
    const float c = ci[row];
    const float sp = (c > 20.f) ? c : log1pf(expf(c));
    const float scale = fminf(1.f, sp / tot);
    for (int k = tid; k < K; k += 256) {
      const float v = W[(size_t)row * K + k] * scale;
      const u16 h = bf16_rne(v);
      const u16 l = bf16_rne(v - bf16_to_f(h));
      D[(size_t)row * 3 * K + k] = h;
      D[(size_t)row * 3 * K + K + k] = h;
      D[(size_t)row * 3 * K + 2 * K + k] = l;
    }
  } else if (b < 512) {  // eW1 split3, 64x512
    const int i = (b - 384) * 256 + tid;
    const int r = i >> 9, k = i & 511;
    const float v = eW1[i];
    const u16 h = bf16_rne(v);
    const u16 l = bf16_rne(v - bf16_to_f(h));
    eW1s[(size_t)r * 1536 + k] = h;
    eW1s[(size_t)r * 1536 + 512 + k] = h;
    eW1s[(size_t)r * 1536 + 1024 + k] = l;
  } else if (b < 640) {  // eW2 split3, 512x64
    const int i = (b - 512) * 256 + tid;
    const int r = i >> 6, k = i & 63;
    const float v = eW2[i];
    const u16 h = bf16_rne(v);
    const u16 l = bf16_rne(v - bf16_to_f(h));
    eW2s[(size_t)r * 192 + k] = h;
    eW2s[(size_t)r * 192 + 64 + k] = h;
    eW2s[(size_t)r * 192 + 128 + k] = l;
  } else if (b < 672) {
    const int i = (b - 640) * 256 + tid;
    dW1b[i] = bf16_rne(dW1[i]);
  } else if (b < 800) {
    const int i = (b - 672) * 256 + tid;
    dW2b[i] = bf16_rne(dW2[i]);
  } else {
    const int i = (b - 800) * 256 + tid;
    oWb[i] = bf16_rne(oW[i]);
  }
}

__global__ void cast_split_x_kernel(const float* __restrict__ x,
                                    u16* __restrict__ xs) {
  const int i = blockIdx.x * 256 + threadIdx.x;
  const int row = i >> 7, c4 = i & 127;
  const float4 v = *(const float4*)(x + (size_t)row * 512 + c4 * 4);
  const float vv[4] = {v.x, v.y, v.z, v.w};
  u16 hv[4], lv[4];
#pragma unroll
  for (int j = 0; j < 4; ++j) {
    hv[j] = bf16_rne(vv[j]);
    lv[j] = bf16_rne(vv[j] - bf16_to_f(hv[j]));
  }
  *(ushort4*)(xs + (size_t)row * 1024 + c4 * 4) =
      make_ushort4(hv[0], hv[1], hv[2], hv[3]);
  *(ushort4*)(xs + (size_t)row * 1024 + 512 + c4 * 4) =
      make_ushort4(lv[0], lv[1], lv[2], lv[3]);
}

// ===========================================================================
// Unified MFMA GEMM (identical to R13).
// ===========================================================================
enum { U_GELU_SPLIT = 0, U_SIG_SPLIT = 1, U_GELU_B16 = 2, U_RECON = 3 };

template <int TM, int TN, int NW, int MODE>
__global__ __launch_bounds__(NW * 64) void gemm_uni(
    const u16* __restrict__ A, const u16* __restrict__ B,
    const float* __restrict__ bias, void* __restrict__ Cv,
    const float* __restrict__ X, float* __restrict__ psum, int Ktot,
    int wrapA, int strideA, int N) {
  __shared__ __align__(16) u16 As[TM * 64];
  __shared__ __align__(16) u16 Bs[TN * 64];
  constexpr int NT = NW * 64;
  constexpr int AIT = (TM * 8) / NT;
  constexpr int BIT = (TN * 8) / NT;
  const int tid = threadIdx.x;
  const int lane = tid & 63, w = tid >> 6;
  const int quad = lane >> 4, l15 = lane & 15;
  const int waveM = (TN == 64) ? w * 64 : (w & 1) * 64;
  const int waveN = (TN == 64) ? 0 : (w >> 1) * 64;
  const int rowBase = blockIdx.y * TM;
  const int colBase = blockIdx.x * TN;

  f32x4 acc[4][4] = {};

  for (int k0 = 0; k0 < Ktot; k0 += 64) {
    const int sk0 = (k0 >= wrapA) ? k0 - wrapA : k0;
    __syncthreads();
#pragma unroll
    for (int i = 0; i < AIT; ++i) {
      const int ch = i * NT + tid;
      const int r = ch >> 3, c = ch & 7, g = c ^ (r & 7);
      load_lds16(A + (size_t)(rowBase + r) * strideA + sk0 + g * 8,
                 (char*)As + ch * 16);
    }
#pragma unroll
    for (int i = 0; i < BIT; ++i) {
      const int ch = i * NT + tid;
      const int r = ch >> 3, c = ch & 7, g = c ^ (r & 7);
      load_lds16(B + (size_t)(colBase + r) * Ktot + k0 + g * 8,
                 (char*)Bs + ch * 16);
    }
    __syncthreads();
#pragma unroll
    for (int ks = 0; ks < 2; ++ks) {
      bf16x8 af[4], bf[4];
      const int ch = ks * 4 + quad;
#pragma unroll
      for (int mi = 0; mi < 4; ++mi) {
        const int rl = waveM + mi * 16 + l15;
        af[mi] = *(const bf16x8*)(As + rl * 64 + (ch ^ (rl & 7)) * 8);
      }
#pragma unroll
      for (int ni = 0; ni < 4; ++ni) {
        const int rl = waveN + ni * 16 + l15;
        bf[ni] = *(const bf16x8*)(Bs + rl * 64 + (ch ^ (rl & 7)) * 8);
      }
#pragma unroll
      for (int mi = 0; mi < 4; ++mi)
#pragma unroll
        for (int ni = 0; ni < 4; ++ni)
          acc[mi][ni] = __builtin_amdgcn_mfma_f32_16x16x32_bf16(
              af[mi], bf[ni], acc[mi][ni], 0, 0, 0);
    }
  }

  if constexpr (MODE == U_GELU_SPLIT || MODE == U_SIG_SPLIT) {
    u16* S = (u16*)Cv;
#pragma unroll
    for (int mi = 0; mi < 4; ++mi)
#pragma unroll
      for (int r = 0; r < 4; ++r) {
        const int row = rowBase + waveM + mi * 16 + quad * 4 + r;
#pragma unroll
        for (int ni = 0; ni < 4; ++ni) {
          const int col = colBase + waveN + ni * 16 + l15;
          const float pre = acc[mi][ni][r] + bias[col];
          const float v = (MODE == U_GELU_SPLIT) ? gelu_f(pre) : sigmoid_f(pre);
          const u16 h = bf16_rne(v);
          const u16 l = bf16_rne(v - bf16_to_f(h));
          S[(size_t)row * 2 * N + col] = h;
          S[(size_t)row * 2 * N + N + col] = l;
        }
      }
  } else if constexpr (MODE == U_GELU_B16) {
    u16* C = (u16*)Cv;
#pragma unroll
    for (int mi = 0; mi < 4; ++mi)
#pragma unroll
      for (int r = 0; r < 4; ++r) {
        const int row = rowBase + waveM + mi * 16 + quad * 4 + r;
#pragma unroll
        for (int ni = 0; ni < 4; ++ni) {
          const int col = colBase + waveN + ni * 16 + l15;
          C[(size_t)row * N + col] =
              bf16_rne(gelu_f(acc[mi][ni][r] + bias[col]));
        }
      }
  } else {  // U_RECON
    float* C = (float*)Cv;
    float local = 0.f;
#pragma unroll
    for (int mi = 0; mi < 4; ++mi)
#pragma unroll
      for (int r = 0; r < 4; ++r) {
        const int row = rowBase + waveM + mi * 16 + quad * 4 + r;
#pragma unroll
        for (int ni = 0; ni < 4; ++ni) {
          const int col = colBase + waveN + ni * 16 + l15;
          const float val = acc[mi][ni][r] + bias[col];
          const float d = val - X[(size_t)row * N + col];
          local += d * d;
          C[(size_t)row * N + col] = val;
        }
      }
#pragma unroll
    for (int o = 32; o > 0; o >>= 1) local += __shfl_down(local, o);
    __shared__ float psh[NW];
    if (lane == 0) psh[w] = local;
    __syncthreads();
    if (tid == 0) {
      float t = 0.f;
#pragma unroll
      for (int i = 0; i < NW; ++i) t += psh[i];
      psum[blockIdx.y * gridDim.x + blockIdx.x] = t;  // unique slot, no atomic
    }
  }
}

// ===========================================================================
// z-level stage-1 distance — R18 dist3z: CT=32 codes x BR=128 rows.
// 4 waves each own 32 ROWS (waveN=w*32) and compute ALL 32 codes ->
// each batch row read by exactly one wave (1x LDS-read redundancy, the
// R17 kernel's dominant cost). Per-row min over all 32 codes is wave-local
// (2 shfl) -> no wred/merge. bufC 16K + bufB 64K = 80KB -> 2 blocks/CU
// (exact 160KB fit). Per iter: MFMA -> epi(+shfl) -> fence -> issue
// stage(t+1) -> store cand from regs -> vmcnt(2) (16 loads drained, 2
// stores in flight) -> barrier.
// ===========================================================================
template <int KT, int CT, int BR, int BTG>
__global__ __launch_bounds__(256) void dist3z_kernel(
    const u16* __restrict__ CB, const u16* __restrict__ ZB,
    const float* __restrict__ cbn, u32* __restrict__ cand, int strideB,
    int ncand) {
  constexpr int CH = KT / 8;               // 32 chunks/row
  constexpr int KSTEPS = KT / 32;          // 8
  constexpr int CSLOTS = (CT * CH) / 256;  // 4
  constexpr int BSLOTS = (BR * CH) / 256;  // 16
  __shared__ __align__(16) u16 bufC[CT * KT];  // 16KB codebook, persistent
  __shared__ __align__(16) u16 bufB[BR * KT];  // 64KB batch tile
  const int tid = threadIdx.x;
  const int lane = tid & 63, w = tid >> 6;
  const int quad = lane >> 4, l15 = lane & 15;
  const int waveN = w * 32;  // this wave's 32 rows
  const int ct = blockIdx.y;
  const int btg = blockIdx.x;
  const int codeBase = ct * CT;

  float cnf[2][4];
#pragma unroll
  for (int mi = 0; mi < 2; ++mi)
#pragma unroll
    for (int r = 0; r < 4; ++r)
      cnf[mi][r] =
          cbn[codeBase + mi * 16 + quad * 4 + r] * 512.0f + 131072.0f;
  asm volatile("" ::: "memory");

  // ---- stage codebook -> bufC, batch tile 0 -> bufB ----
#pragma unroll
  for (int i = 0; i < CSLOTS; ++i) {
    const int ch = i * 256 + tid;
    const int r = ch / CH, c = ch % CH, g = c ^ (r & 7);
    load_lds16(CB + (size_t)(codeBase + r) * KT + g * 8, (char*)bufC + ch * 16);
  }
  {
    const int rowBase0 = btg * BTG * BR;
#pragma unroll
    for (int i = 0; i < BSLOTS; ++i) {
      const int ch = i * 256 + tid;
      const int r = ch / CH, c = ch % CH, g = c ^ (r & 7);
      load_lds16(ZB + (size_t)(rowBase0 + r) * strideB + g * 8,
                 (char*)bufB + ch * 16);
    }
  }
  wait_vmcnt<0>();
  barrier_raw();

  // ---- hoist A fragments (all 32 codes; 64 VGPR); bufC never touched again
  bf16x8 af[KSTEPS][2];
#pragma unroll
  for (int kk = 0; kk < KSTEPS; ++kk)
#pragma unroll
    for (int mi = 0; mi < 2; ++mi) {
      const int rl = mi * 16 + l15;
      const int sw = (kk * 4 + quad) ^ (rl & 7);
      af[kk][mi] = *(const bf16x8*)(bufC + rl * KT + sw * 8);
    }

#pragma unroll 1
  for (int bt = 0; bt < BTG; ++bt) {
    const int rowBase = (btg * BTG + bt) * BR;

    // ---- MFMA over this wave's 32 rows x all 32 codes ----
    f32x4 acc[2][2] = {};
#pragma unroll
    for (int kk = 0; kk < KSTEPS; ++kk) {
      bf16x8 bf[2];
#pragma unroll
      for (int ni = 0; ni < 2; ++ni) {
        const int rn = waveN + ni * 16 + l15;
        const int sw = (kk * 4 + quad) ^ (rn & 7);
        bf[ni] = *(const bf16x8*)(bufB + rn * KT + sw * 8);
      }
#pragma unroll
      for (int mi = 0; mi < 2; ++mi)
#pragma unroll
        for (int ni = 0; ni < 2; ++ni)
          acc[mi][ni] = __builtin_amdgcn_mfma_f32_16x16x32_bf16(
              af[kk][mi], bf[ni], acc[mi][ni], 0, 0, 0);
    }

    // ---- epilogue: per-row min over all 32 codes (wave-local) ----
    u32 best[2];
#pragma unroll
    for (int ni = 0; ni < 2; ++ni) {
      u32 b0 = ~0u;
#pragma unroll
      for (int mi = 0; mi < 2; ++mi)
#pragma unroll
        for (int r = 0; r < 4; ++r) {
          const float kf = fmaf(acc[mi][ni][r], -1024.0f, cnf[mi][r]);
          u32 iv = (u32)kf;
          iv = iv > 0xFFFFFu ? 0xFFFFFu : iv;
          const u32 key = (iv << 12) | (codeBase + mi * 16 + quad * 4 + r);
          b0 = min(b0, key);
        }
      b0 = min(b0, (u32)__shfl_xor(b0, 16));
      b0 = min(b0, (u32)__shfl_xor(b0, 32));
      best[ni] = b0;
    }
    // bufB reads retired by all waves, then barrier
    lds_fence_barrier_pre();

    // ---- issue next tile's staging, then cand stores (stores newest) ----
    if (bt + 1 < BTG) {
      const int rowBaseN = rowBase + BR;
#pragma unroll
      for (int i = 0; i < BSLOTS; ++i) {
        const int ch = i * 256 + tid;
        const int r = ch / CH, c = ch % CH, g = c ^ (r & 7);
        load_lds16(ZB + (size_t)(rowBaseN + r) * strideB + g * 8,
                   (char*)bufB + ch * 16);
      }
    }
    if (quad == 0) {
#pragma unroll
      for (int ni = 0; ni < 2; ++ni) {
        const int row = rowBase + waveN + ni * 16 + l15;
        cand[(size_t)row * ncand + ct] = best[ni];
      }
    }
    wait_vmcnt<2>();  // 16 stage loads drained; 2 cand stores stay in flight
    barrier_raw();    // bufB(t+1) visible to all waves
  }
}

// ===========================================================================
// q-level stage-1 distance — R17 dist2z (unchanged): 64 codes x 64 rows,
// 4 blocks/CU. Top-1 per tile -> cand[row*32+ct].
// ===========================================================================
template <int KT, int CT, int BR, int BTG>
__global__ __launch_bounds__(256) void dist2z_kernel(
    const u16* __restrict__ CB, const u16* __restrict__ ZB,
    const float* __restrict__ cbn, u32* __restrict__ cand, int strideB,
    int ncand) {
  constexpr int CH = KT / 8;               // 16B-chunks per row
  constexpr int KSTEPS = KT / 32;
  constexpr int CSLOTS = (CT * CH) / 256;
  constexpr int BSLOTS = (BR * CH) / 256;
  __shared__ __align__(16) u16 bufC[CT * KT];  // codebook, persistent
  __shared__ __align__(16) u16 bufB[BR * KT];  // batch tile
  __shared__ u32 wred[BR * 2];
  const int tid = threadIdx.x;
  const int lane = tid & 63, w = tid >> 6;
  const int quad = lane >> 4, l15 = lane & 15;
  const int waveM = (w & 1) * 32;   // code half (32 codes)
  const int waveN = (w >> 1) * 32;  // batch half (32 rows)
  const int ct = blockIdx.y;
  const int btg = blockIdx.x;
  const int codeBase = ct * CT;

  float cnf[2][4];
#pragma unroll
  for (int mi = 0; mi < 2; ++mi)
#pragma unroll
    for (int r = 0; r < 4; ++r)
      cnf[mi][r] =
          cbn[codeBase + waveM + mi * 16 + quad * 4 + r] * 512.0f + 131072.0f;
  asm volatile("" ::: "memory");

  // ---- stage codebook -> bufC, batch tile 0 -> bufB ----
#pragma unroll
  for (int i = 0; i < CSLOTS; ++i) {
    const int ch = i * 256 + tid;
    const int r = ch / CH, c = ch % CH, g = c ^ (r & 7);
    load_lds16(CB + (size_t)(codeBase + r) * KT + g * 8, (char*)bufC + ch * 16);
  }
  {
    const int rowBase0 = btg * BTG * BR;
#pragma unroll
    for (int i = 0; i < BSLOTS; ++i) {
      const int ch = i * 256 + tid;
      const int r = ch / CH, c = ch % CH, g = c ^ (r & 7);
      load_lds16(ZB + (size_t)(rowBase0 + r) * strideB + g * 8,
                 (char*)bufB + ch * 16);
    }
  }
  wait_vmcnt<0>();
  barrier_raw();

  // ---- hoist A fragments; bufC never written again ----
  bf16x8 af[KSTEPS][2];
#pragma unroll
  for (int kk = 0; kk < KSTEPS; ++kk)
#pragma unroll
    for (int mi = 0; mi < 2; ++mi) {
      const int rl = waveM + mi * 16 + l15;
      const int sw = (kk * 4 + quad) ^ (rl & 7);
      af[kk][mi] = *(const bf16x8*)(bufC + rl * KT + sw * 8);
    }

#pragma unroll 1
  for (int bt = 0; bt < BTG; ++bt) {
    const int rowBase = (btg * BTG + bt) * BR;

    // ---- MFMA over bufB(bt) ----
    f32x4 acc[2][2] = {};
#pragma unroll
    for (int kk = 0; kk < KSTEPS; ++kk) {
      bf16x8 bf[2];
#pragma unroll
      for (int ni = 0; ni < 2; ++ni) {
        const int rn = waveN + ni * 16 + l15;
        const int sw = (kk * 4 + quad) ^ (rn & 7);
        bf[ni] = *(const bf16x8*)(bufB + rn * KT + sw * 8);
      }
#pragma unroll
      for (int mi = 0; mi < 2; ++mi)
#pragma unroll
        for (int ni = 0; ni < 2; ++ni)
          acc[mi][ni] = __builtin_amdgcn_mfma_f32_16x16x32_bf16(
              af[kk][mi], bf[ni], acc[mi][ni], 0, 0, 0);
    }

    // ---- epilogue: top-1 per batch row over this wave's 32 codes ----
#pragma unroll
    for (int ni = 0; ni < 2; ++ni) {
      u32 b0 = ~0u;
#pragma unroll
      for (int mi = 0; mi < 2; ++mi)
#pragma unroll
        for (int r = 0; r < 4; ++r) {
          const float kf = fmaf(acc[mi][ni][r], -1024.0f, cnf[mi][r]);
          u32 iv = (u32)kf;
          iv = iv > 0xFFFFFu ? 0xFFFFFu : iv;
          const u32 key =
              (iv << 12) | (codeBase + waveM + mi * 16 + quad * 4 + r);
          b0 = min(b0, key);
        }
      b0 = min(b0, (u32)__shfl_xor(b0, 16));
      b0 = min(b0, (u32)__shfl_xor(b0, 32));
      if (quad == 0) {
        const int rloc = waveN + ni * 16 + l15;
        wred[rloc * 2 + (w & 1)] = b0;
      }
    }
    // bufB reads + wred writes retired, then barrier
    lds_fence_barrier_pre();

    // ---- issue next tile's staging (DMA runs under the merge) ----
    if (bt + 1 < BTG) {
      const int rowBaseN = rowBase + BR;
#pragma unroll
      for (int i = 0; i < BSLOTS; ++i) {
        const int ch = i * 256 + tid;
        const int r = ch / CH, c = ch % CH, g = c ^ (r & 7);
        load_lds16(ZB + (size_t)(rowBaseN + r) * strideB + g * 8,
                   (char*)bufB + ch * 16);
      }
    }
    // ---- merge + store (reads wred(bt), safe vs stage: different region) --
    if (tid < BR) {
      const u32 m0 = min(wred[tid * 2 + 0], wred[tid * 2 + 1]);
      cand[(size_t)(rowBase + tid) * ncand + ct] = m0;
    }
    wait_vmcnt<1>();          // stages drained (cand store stays in flight)
    lds_fence_barrier_pre();  // visible to all; merge reads drained
  }
}

// ===========================================================================
// Stage-2 rerank — R18: selection via 8x wave-min-scan over NK=ceil(NC/64)
// keys per lane (registers only, no LDS/syncthreads). Supports NC=128 (z)
// and NC=32 (q). Keys are unique (code id in low 12 bits).
// ===========================================================================
template <int K, int NC, int LEVEL>
__global__ __launch_bounds__(256, 4) void rerank_kernel(
    const u32* __restrict__ cand, const u16* __restrict__ zes,
    const float* __restrict__ cb, const float* __restrict__ cbn,
    float* __restrict__ outq, u16* __restrict__ wsq,
    float* __restrict__ out_idx, float* __restrict__ psum) {
  constexpr int DV = K / 32;  // float4-chunks per lane dot slice (8 z / 4 q)
  constexpr int MV = K / 64;  // MSE elems per lane (4 z / 2 q)
  constexpr int NK = (NC + 63) / 64;  // keys per lane (2 z / 1 q)
  const int w = threadIdx.x >> 6, lane = threadIdx.x & 63;
  const int row = blockIdx.x * 4 + w;
  const int g = lane >> 3, sub = lane & 7;

  const u16* zr = zes + (size_t)row * 2 * K;

  // ---- phase 1: batch-issue all row-dependent loads ----
  ushort4 zh[DV], zl[DV];
#pragma unroll
  for (int i = 0; i < DV; ++i) {
    zh[i] = *(const ushort4*)(zr + sub * (K / 8) + 4 * i);
    zl[i] = *(const ushort4*)(zr + K + sub * (K / 8) + 4 * i);
  }
  float zmse[MV];
#pragma unroll
  for (int i = 0; i < MV; ++i) {
    const int c = lane + 64 * i;
    zmse[i] = bf16_to_f(zr[c]) + bf16_to_f(zr[K + c]);
  }
  u32 mk0 = (lane < NC) ? cand[(size_t)row * NC + lane] : ~0u;
  u32 mk1 = (NK == 2) ? cand[(size_t)row * NC + 64 + lane] : ~0u;

  // ---- phase 2: top-8 via 8x wave-min-scan (registers only) ----
  unsigned topcode[8];
#pragma unroll
  for (int t = 0; t < 8; ++t) {
    u32 m = min(mk0, mk1);
#pragma unroll
    for (int off = 1; off < 64; off <<= 1) m = min(m, (u32)__shfl_xor(m, off));
    topcode[t] = m & 0xFFFu;
    if (mk0 == m) mk0 = ~0u;
    else if (mk1 == m) mk1 = ~0u;
  }
  unsigned ci = topcode[0];
#pragma unroll
  for (int t = 1; t < 8; ++t) ci = (g == t) ? topcode[t] : ci;

  // ---- phase 3: exact f32 dot for this group's candidate ----
  const float* cr = cb + (size_t)ci * K;
  float dot = 0.f;
#pragma unroll
  for (int i = 0; i < DV; ++i) {
    const float4 cv = *(const float4*)(cr + sub * (K / 8) + 4 * i);
    dot = fmaf(bf16_to_f(zh[i].x) + bf16_to_f(zl[i].x), cv.x, dot);
    dot = fmaf(bf16_to_f(zh[i].y) + bf16_to_f(zl[i].y), cv.y, dot);
    dot = fmaf(bf16_to_f(zh[i].z) + bf16_to_f(zl[i].z), cv.z, dot);
    dot = fmaf(bf16_to_f(zh[i].w) + bf16_to_f(zl[i].w), cv.w, dot);
  }
#pragma unroll
  for (int off = 1; off < 8; off <<= 1) dot += __shfl_xor(dot, off);
  u64 k2 = pack_key(cbn[ci] - 2.0f * dot, ci);
#pragma unroll
  for (int off = 8; off < 64; off <<= 1) k2 = min64(k2, __shfl_xor(k2, off));
  const unsigned best = (unsigned)k2;
  if (lane == 0) out_idx[row] = (float)best;

  // ---- phase 4: gather best row, MSE + writes ----
  const float* br = cb + (size_t)best * K;
  float local = 0.f;
#pragma unroll
  for (int i = 0; i < MV; ++i) {
    const int c = lane + 64 * i;
    const float v = br[c];
    const float d = zmse[i] - v;
    local += d * d;
    outq[(size_t)row * K + c] = v;
    if (LEVEL == 0) {
      const u16 h = bf16_rne(v);
      wsq[(size_t)row * 2 * K + c] = h;
      wsq[(size_t)row * 2 * K + K + c] = bf16_rne(v - bf16_to_f(h));
    } else {
      wsq[(size_t)row * K + c] = bf16_rne(v);
    }
  }
#pragma unroll
  for (int o = 32; o > 0; o >>= 1) local += __shfl_down(local, o);
  __shared__ float p[4];
  if (lane == 0) p[w] = local;
  __syncthreads();
  if (threadIdx.x == 0) psum[blockIdx.x] = p[0] + p[1] + p[2] + p[3];
}

// ===========================================================================
// Finalize: sum the per-block partials (8192 z + 8192 q + 1024 recon).
// ===========================================================================
__global__ void finalize_kernel(const float* __restrict__ psumZ,
                                const float* __restrict__ psumQ,
                                const float* __restrict__ psumR,
                                float* __restrict__ out) {
  const int tid = threadIdx.x;
  float sz = 0.f, sq = 0.f, sr = 0.f;
  for (int i = tid; i < 8192; i += 256) {
    sz += psumZ[i];
    sq += psumQ[i];
  }
  for (int i = tid; i < 1024; i += 256) sr += psumR[i];
#pragma unroll
  for (int o = 32; o > 0; o >>= 1) {
    sz += __shfl_down(sz, o);
    sq += __shfl_down(sq, o);
    sr += __shfl_down(sr, o);
  }
  __shared__ float pz[4], pq[4], pr[4];
  if ((tid & 63) == 0) {
    pz[tid >> 6] = sz;
    pq[tid >> 6] = sq;
    pr[tid >> 6] = sr;
  }
  __syncthreads();
  if (tid == 0) {
    const float cz = (pz[0] + pz[1] + pz[2] + pz[3]) / ((float)kBatch * 256.f);
    const float cq = (pq[0] + pq[1] + pq[2] + pq[3]) / ((float)kBatch * 128.f);
    const float rec = (pr[0] + pr[1] + pr[2] + pr[3]) / ((float)kBatch * 512.f);
    out[0] = rec + 0.5f * cz + 0.5f * cq;
    out[1] = rec;
    out[2] = cz;
    out[3] = cz;
    out[4] = cq;
    out[5] = cq;
  }
}

}  // namespace

extern "C" void kernel_launch(void* const* d_in, const int* in_sizes, int n_in,
                              void* d_out, int out_size, void* d_ws,
                              size_t ws_size, hipStream_t stream) {
  const float* x   = (const float*)d_in[0];
  const float* eW1 = (const float*)d_in[1];
  const float* eb1 = (const float*)d_in[2];
  const float* eW2 = (const float*)d_in[3];
  const float* eb2 = (const float*)d_in[4];
  const float* zW  = (const float*)d_in[5];
  const float* zb  = (const float*)d_in[6];
  const float* zci = (const float*)d_in[7];
  const float* zcb = (const float*)d_in[8];
  const float* qW  = (const float*)d_in[9];
  const float* qb  = (const float*)d_in[10];
  const float* qci = (const float*)d_in[11];
  const float* qcb = (const float*)d_in[12];
  const float* dW1 = (const float*)d_in[13];
  const float* db1 = (const float*)d_in[14];
  const float* dW2 = (const float*)d_in[15];
  const float* db2 = (const float*)d_in[16];
  const float* oW  = (const float*)d_in[17];
  const float* ob  = (const float*)d_in[18];

  float* out = (float*)d_out;
  float* out_xr = out + 6;
  float* out_zq = out_xr + (size_t)32768 * 512;
  float* out_qq = out_zq + (size_t)32768 * 256;
  float* out_zi = out_qq + (size_t)32768 * 128;
  float* out_qi = out_zi + 32768;

  // ---- workspace layout ---------------------------------------------------
  char* wsb = (char*)d_ws;
  u16*  zWns = (u16*) (wsb + 0x0000000);  // 256 x 1536  768K
  u16*  qWns = (u16*) (wsb + 0x00C0000);  // 128 x 768   192K
  u16*  eW1s = (u16*) (wsb + 0x00F0000);  // 64 x 1536   192K
  u16*  eW2s = (u16*) (wsb + 0x0120000);  // 512 x 192   192K
  u16*  dW1b = (u16*) (wsb + 0x0150000);  // 64x128       16K
  u16*  dW2b = (u16*) (wsb + 0x0154000);  // 512x64       64K
  u16*  oWb  = (u16*) (wsb + 0x0164000);  // 512x512     512K
  u16*  zcbh = (u16*) (wsb + 0x01E4000);  // 4096x256      2M
  u16*  qcbh = (u16*) (wsb + 0x03E4000);  // 2048x128    512K
  float* zcbn = (float*)(wsb + 0x0464000); // 16K
  float* qcbn = (float*)(wsb + 0x0468000); // 8K
  float* psumR = (float*)(wsb + 0x046B000); // 1024 f32 = 4K
  float* psumZ = (float*)(wsb + 0x0470000); // 8192 f32 = 32K
  float* psumQ = (float*)(wsb + 0x0478000); // 8192 f32 = 32K
  // time-windowed regions:
  u16*  h1s  = (u16*) (wsb + 0x0480000);  // 8M  [enc1 -> enc2]
  u16*  h1b  = (u16*) (wsb + 0x0480000);  //   4M [dec1 -> dec2]
  u16*  zes  = (u16*) (wsb + 0x0C80000);  // 32M [zproj -> zdist,zrerank]
  u16*  qes  = (u16*) (wsb + 0x0C80000);  //   16M [qproj -> qdist,qrerank]
  u16*  hb   = (u16*) (wsb + 0x0C80000);  //   32M [dec2 -> recon]
  u16*  xs   = (u16*) (wsb + 0x2C80000);  // 64M [cast -> enc1]
  u16*  hs   = (u16*) (wsb + 0x2C80000);  //   64M [enc2 -> zproj] (ends 0x6C80000)
  u32*  candq = (u32*)(wsb + 0x2C80000);  //   4M [qdist -> qrerank]
  u16*  zqs  = (u16*) (wsb + 0x3480000);  //   32M [zrerank -> qproj]
  u16*  qqb  = (u16*) (wsb + 0x5480000);  //   8M [qrerank -> dec1]
  u32*  candz = (u32*)(wsb + 0x5C80000);  //  16M [zdist -> zrerank] (<= hs end)

  // ---- prep (3 launches; no memset needed — partials are plain stores) ----
  prep_cb_kernel<<<1536, 256, 0, stream>>>(zcb, zcbh, zcbn, qcb, qcbh, qcbn);
  prep_w_kernel<<<1824, 256, 0, stream>>>(zW, zci, qW, qci, eW1, eW2, zWns,
                                          qWns, eW1s, eW2s, dW1, dW2, oW,
                                          dW1b, dW2b, oWb);
  cast_split_x_kernel<<<16384, 256, 0, stream>>>(x, xs);

  // ---- encoder ----
  gemm_uni<128, 64, 2, U_GELU_SPLIT><<<dim3(1, 256), 128, 0, stream>>>(
      xs, eW1s, eb1, h1s, nullptr, nullptr, 1536, 1024, 1024, 64);
  gemm_uni<128, 128, 4, U_GELU_SPLIT><<<dim3(4, 256), 256, 0, stream>>>(
      h1s, eW2s, eb2, hs, nullptr, nullptr, 192, 128, 128, 512);
  gemm_uni<128, 128, 4, U_SIG_SPLIT><<<dim3(2, 256), 256, 0, stream>>>(
      hs, zWns, zb, zes, nullptr, nullptr, 1536, 1024, 1024, 256);

  // ---- z quantize: dist3z 32x128 tiles, grid (8,128) = 1024 blocks,
  //      2 blocks/CU (LDS 80K x2 = 160K exact); top-1/tile -> cand[row*128+ct]
  dist3z_kernel<256, 32, 128, 32><<<dim3(8, 128), 256, 0, stream>>>(
      zcbh, zes, zcbn, candz, 512, 128);
  rerank_kernel<256, 128, 0><<<8192, 256, 0, stream>>>(
      candz, zes, zcb, zcbn, out_zq, zqs, out_zi, psumZ);

  // ---- q level: dist2z 64x64 tiles, grid (32,32) = 1024 blocks = 4/CU ----
  gemm_uni<128, 128, 4, U_SIG_SPLIT><<<dim3(1, 256), 256, 0, stream>>>(
      zqs, qWns, qb, qes, nullptr, nullptr, 768, 512, 512, 128);
  dist2z_kernel<128, 64, 64, 16><<<dim3(32, 32), 256, 0, stream>>>(
      qcbh, qes, qcbn, candq, 256, 32);
  rerank_kernel<128, 32, 1><<<8192, 256, 0, stream>>>(
      candq, qes, qcb, qcbn, out_qq, qqb, out_qi, psumQ);

  // ---- decoder ----
  gemm_uni<128, 64, 2, U_GELU_B16><<<dim3(1, 256), 128, 0, stream>>>(
      qqb, dW1b, db1, h1b, nullptr, nullptr, 128, 1 << 30, 128, 64);
  gemm_uni<128, 128, 4, U_GELU_B16><<<dim3(4, 256), 256, 0, stream>>>(
      h1b, dW2b, db2, hb, nullptr, nullptr, 64, 1 << 30, 64, 512);
  gemm_uni<128, 128, 4, U_RECON><<<dim3(4, 256), 256, 0, stream>>>(
      hb, oWb, ob, out_xr, x, psumR, 512, 1 << 30, 512, 512);

  finalize_kernel<<<1, 256, 0, stream>>>(psumZ, psumQ, psumR, out);

  (void)in_sizes; (void)n_in; (void)out_size; (void)ws_size;
}

// Round 11
// 701.657 us; speedup vs baseline: 1.0024x; 1.0024x over previous
//
#include <hip/hip_runtime.h>

typedef unsigned long long u64;
typedef unsigned short u16;
typedef unsigned int u32;

// ---------------------------------------------------------------------------
// HierarchicalLFQHVQVAE forward — R19.
// Base = R17 (667 us). R18 REGRESSED (703): per-row LDS reads are INVARIANT
// under the (codes x rows) decomposition flip — (CT/32)*(4096/CT) = 128 —
// while staging traffic doubled (4096/CT blocks re-stage each row). Ledger:
// maximize codes/block under the VGPR hoist cap = R17's dist2z<64,64>.
// R19 = R17 reverted + ONE change in the shared dist2z template:
//   reorder the iteration so the stage(t+1) DMA is issued right after the
//   post-MFMA barrier and the register-only epilogue (min+shfl+wred) runs
//   UNDER the DMA (was: epi before barrier, DMA covered only by ~100cyc
//   merge). Same 2 barriers/iter; vmcnt(0) before barrier B (the t-1 cand
//   store is older than the stage loads, so a counted wait can't help).
// Everything else byte-identical to R17.
// ---------------------------------------------------------------------------

namespace {

constexpr int kBatch = 32768;

__device__ __forceinline__ float gelu_f(float x) {
  return 0.5f * x * (1.0f + erff(x * 0.70710678118654752440f));
}
__device__ __forceinline__ float sigmoid_f(float x) {
  return 1.0f / (1.0f + expf(-x));
}
__device__ __forceinline__ u64 pack_key(float d, unsigned j) {
  unsigned u = __float_as_uint(d);
  u = (u & 0x80000000u) ? ~u : (u | 0x80000000u);
  return ((u64)u << 32) | j;
}
__device__ __forceinline__ u16 bf16_rne(float x) {
  unsigned u = __float_as_uint(x);
  unsigned r = (u + 0x7FFFu + ((u >> 16) & 1u)) >> 16;
  return (u16)r;
}
__device__ __forceinline__ float bf16_to_f(u16 h) {
  return __uint_as_float((unsigned)h << 16);
}
__device__ __forceinline__ u64 min64(u64 a, u64 b) { return a < b ? a : b; }

__device__ __forceinline__ void load_lds16(const void* g, void* l) {
  __builtin_amdgcn_global_load_lds(
      (const __attribute__((address_space(1))) void*)g,
      (__attribute__((address_space(3))) void*)l, 16, 0, 0);
}

template <int N>
__device__ __forceinline__ void wait_vmcnt() {
  if constexpr (N == 0) {
    asm volatile("s_waitcnt vmcnt(0)" ::: "memory");
  } else if constexpr (N == 1) {
    asm volatile("s_waitcnt vmcnt(1)" ::: "memory");
  } else if constexpr (N == 8) {
    asm volatile("s_waitcnt vmcnt(8)" ::: "memory");
  } else if constexpr (N == 16) {
    asm volatile("s_waitcnt vmcnt(16)" ::: "memory");
  }
}

__device__ __forceinline__ void lds_fence_barrier_pre() {
  // order: all prior LDS ops retired, then barrier
  asm volatile("s_waitcnt lgkmcnt(0)" ::: "memory");
  __builtin_amdgcn_sched_barrier(0);
  __builtin_amdgcn_s_barrier();
  asm volatile("" ::: "memory");  // no LDS op hoists above the barrier
  __builtin_amdgcn_sched_barrier(0);
}

__device__ __forceinline__ void full_fence_barrier() {
  // order: all prior LDS ops + VMEM (incl. global_load_lds) retired, barrier
  asm volatile("s_waitcnt vmcnt(0) lgkmcnt(0)" ::: "memory");
  __builtin_amdgcn_sched_barrier(0);
  __builtin_amdgcn_s_barrier();
  asm volatile("" ::: "memory");
  __builtin_amdgcn_sched_barrier(0);
}

__device__ __forceinline__ void barrier_raw() {
  __builtin_amdgcn_sched_barrier(0);
  __builtin_amdgcn_s_barrier();
  asm volatile("" ::: "memory");  // no LDS op hoists above the barrier
  __builtin_amdgcn_sched_barrier(0);
}

typedef short bf16x8 __attribute__((ext_vector_type(8)));
typedef float f32x4 __attribute__((ext_vector_type(4)));

// ===========================================================================
// Prep (3 kernels) — identical to R6
// ===========================================================================
__global__ void prep_cb_kernel(const float* __restrict__ zcb,
                               u16* __restrict__ zcbh, float* __restrict__ zcbn,
                               const float* __restrict__ qcb,
                               u16* __restrict__ qcbh, float* __restrict__ qcbn) {
  int b = blockIdx.x;
  const float* cb;
  u16* cbh;
  float* cbn;
  int K;
  if (b < 1024) { cb = zcb; cbh = zcbh; cbn = zcbn; K = 256; }
  else { b -= 1024; cb = qcb; cbh = qcbh; cbn = qcbn; K = 128; }
  const int row = b * 4 + (threadIdx.x >> 6);
  const int lane = threadIdx.x & 63;
  double s = 0.0;
  for (int k = lane; k < K; k += 64) {
    const float v = cb[(size_t)row * K + k];
    cbh[(size_t)row * K + k] = bf16_rne(v);
    s += (double)v * (double)v;
  }
#pragma unroll
  for (int o = 32; o > 0; o >>= 1) s += __shfl_down(s, o);
  if (lane == 0) cbn[row] = (float)s;
}

__global__ void prep_w_kernel(
    const float* __restrict__ zW, const float* __restrict__ zci,
    const float* __restrict__ qW, const float* __restrict__ qci,
    const float* __restrict__ eW1, const float* __restrict__ eW2,
    u16* __restrict__ zWns, u16* __restrict__ qWns, u16* __restrict__ eW1s,
    u16* __restrict__ eW2s, const float* __restrict__ dW1,
    const float* __restrict__ dW2, const float* __restrict__ oW,
    u16* __restrict__ dW1b, u16* __restrict__ dW2b, u16* __restrict__ oWb) {
  const int b = blockIdx.x;
  const int tid = threadIdx.x;
  if (b < 384) {
    const float* W;
    const float* ci;
    u16* D;
    int K, row;
    if (b < 256) { W = zW; ci = zci; D = zWns; K = 512; row = b; }
    else { W = qW; ci = qci; D = qWns; K = 256; row = b - 256; }
    float s = 0.f;
    for (int k = tid; k < K; k += 256) s += fabsf(W[(size_t)row * K + k]);
#pragma unroll
    for (int o = 32; o > 0; o >>= 1) s += __shfl_down(s, o);
    __shared__ float p[4];
    if ((tid & 63) == 0) p[tid >> 6] = s;
    __syncthreads();
    const float tot = p[0] + p[1] + p[2] + p[3];
    const float c = ci[row];
    const float sp = (c > 20.f) ? c : log1pf(expf(c));
    const float scale = fminf(1.f, sp / tot);
    for (int k = tid; k < K; k += 256) {
      const float v = W[(size_t)row * K + k] * scale;
      const u16 h = bf16_rne(v);
      const u16 l = bf16_rne(v - bf16_to_f(h));
      D[(size_t)row * 3 * K + k] = h;
      D[(size_t)row * 3 * K + K + k] = h;
      D[(size_t)row * 3 * K + 2 * K + k] = l;
    }
  } else if (b < 512) {  // eW1 split3, 64x512
    const int i = (b - 384) * 256 + tid;
    const int r = i >> 9, k = i & 511;
    const float v = eW1[i];
    const u16 h = bf16_rne(v);
    const u16 l = bf16_rne(v - bf16_to_f(h));
    eW1s[(size_t)r * 1536 + k] = h;
    eW1s[(size_t)r * 1536 + 512 + k] = h;
    eW1s[(size_t)r * 1536 + 1024 + k] = l;
  } else if (b < 640) {  // eW2 split3, 512x64
    const int i = (b - 512) * 256 + tid;
    const int r = i >> 6, k = i & 63;
    const float v = eW2[i];
    const u16 h = bf16_rne(v);
    const u16 l = bf16_rne(v - bf16_to_f(h));
    eW2s[(size_t)r * 192 + k] = h;
    eW2s[(size_t)r * 192 + 64 + k] = h;
    eW2s[(size_t)r * 192 + 128 + k] = l;
  } else if (b < 672) {
    const int i = (b - 640) * 256 + tid;
    dW1b[i] = bf16_rne(dW1[i]);
  } else if (b < 800) {
    const int i = (b - 672) * 256 + tid;
    dW2b[i] = bf16_rne(dW2[i]);
  } else {
    const int i = (b - 800) * 256 + tid;
    oWb[i] = bf16_rne(oW[i]);
  }
}

__global__ void cast_split_x_kernel(const float* __restrict__ x,
                                    u16* __restrict__ xs) {
  const int i = blockIdx.x * 256 + threadIdx.x;
  const int row = i >> 7, c4 = i & 127;
  const float4 v = *(const float4*)(x + (size_t)row * 512 + c4 * 4);
  const float vv[4] = {v.x, v.y, v.z, v.w};
  u16 hv[4], lv[4];
#pragma unroll
  for (int j = 0; j < 4; ++j) {
    hv[j] = bf16_rne(vv[j]);
    lv[j] = bf16_rne(vv[j] - bf16_to_f(hv[j]));
  }
  *(ushort4*)(xs + (size_t)row * 1024 + c4 * 4) =
      make_ushort4(hv[0], hv[1], hv[2], hv[3]);
  *(ushort4*)(xs + (size_t)row * 1024 + 512 + c4 * 4) =
      make_ushort4(lv[0], lv[1], lv[2], lv[3]);
}

// ===========================================================================
// Unified MFMA GEMM (identical to R13).
// ===========================================================================
enum { U_GELU_SPLIT = 0, U_SIG_SPLIT = 1, U_GELU_B16 = 2, U_RECON = 3 };

template <int TM, int TN, int NW, int MODE>
__global__ __launch_bounds__(NW * 64) void gemm_uni(
    const u16* __restrict__ A, const u16* __restrict__ B,
    const float* __restrict__ bias, void* __restrict__ Cv,
    const float* __restrict__ X, float* __restrict__ psum, int Ktot,
    int wrapA, int strideA, int N) {
  __shared__ __align__(16) u16 As[TM * 64];
  __shared__ __align__(16) u16 Bs[TN * 64];
  constexpr int NT = NW * 64;
  constexpr int AIT = (TM * 8) / NT;
  constexpr int BIT = (TN * 8) / NT;
  const int tid = threadIdx.x;
  const int lane = tid & 63, w = tid >> 6;
  const int quad = lane >> 4, l15 = lane & 15;
  const int waveM = (TN == 64) ? w * 64 : (w & 1) * 64;
  const int waveN = (TN == 64) ? 0 : (w >> 1) * 64;
  const int rowBase = blockIdx.y * TM;
  const int colBase = blockIdx.x * TN;

  f32x4 acc[4][4] = {};

  for (int k0 = 0; k0 < Ktot; k0 += 64) {
    const int sk0 = (k0 >= wrapA) ? k0 - wrapA : k0;
    __syncthreads();
#pragma unroll
    for (int i = 0; i < AIT; ++i) {
      const int ch = i * NT + tid;
      const int r = ch >> 3, c = ch & 7, g = c ^ (r & 7);
      load_lds16(A + (size_t)(rowBase + r) * strideA + sk0 + g * 8,
                 (char*)As + ch * 16);
    }
#pragma unroll
    for (int i = 0; i < BIT; ++i) {
      const int ch = i * NT + tid;
      const int r = ch >> 3, c = ch & 7, g = c ^ (r & 7);
      load_lds16(B + (size_t)(colBase + r) * Ktot + k0 + g * 8,
                 (char*)Bs + ch * 16);
    }
    __syncthreads();
#pragma unroll
    for (int ks = 0; ks < 2; ++ks) {
      bf16x8 af[4], bf[4];
      const int ch = ks * 4 + quad;
#pragma unroll
      for (int mi = 0; mi < 4; ++mi) {
        const int rl = waveM + mi * 16 + l15;
        af[mi] = *(const bf16x8*)(As + rl * 64 + (ch ^ (rl & 7)) * 8);
      }
#pragma unroll
      for (int ni = 0; ni < 4; ++ni) {
        const int rl = waveN + ni * 16 + l15;
        bf[ni] = *(const bf16x8*)(Bs + rl * 64 + (ch ^ (rl & 7)) * 8);
      }
#pragma unroll
      for (int mi = 0; mi < 4; ++mi)
#pragma unroll
        for (int ni = 0; ni < 4; ++ni)
          acc[mi][ni] = __builtin_amdgcn_mfma_f32_16x16x32_bf16(
              af[mi], bf[ni], acc[mi][ni], 0, 0, 0);
    }
  }

  if constexpr (MODE == U_GELU_SPLIT || MODE == U_SIG_SPLIT) {
    u16* S = (u16*)Cv;
#pragma unroll
    for (int mi = 0; mi < 4; ++mi)
#pragma unroll
      for (int r = 0; r < 4; ++r) {
        const int row = rowBase + waveM + mi * 16 + quad * 4 + r;
#pragma unroll
        for (int ni = 0; ni < 4; ++ni) {
          const int col = colBase + waveN + ni * 16 + l15;
          const float pre = acc[mi][ni][r] + bias[col];
          const float v = (MODE == U_GELU_SPLIT) ? gelu_f(pre) : sigmoid_f(pre);
          const u16 h = bf16_rne(v);
          const u16 l = bf16_rne(v - bf16_to_f(h));
          S[(size_t)row * 2 * N + col] = h;
          S[(size_t)row * 2 * N + N + col] = l;
        }
      }
  } else if constexpr (MODE == U_GELU_B16) {
    u16* C = (u16*)Cv;
#pragma unroll
    for (int mi = 0; mi < 4; ++mi)
#pragma unroll
      for (int r = 0; r < 4; ++r) {
        const int row = rowBase + waveM + mi * 16 + quad * 4 + r;
#pragma unroll
        for (int ni = 0; ni < 4; ++ni) {
          const int col = colBase + waveN + ni * 16 + l15;
          C[(size_t)row * N + col] =
              bf16_rne(gelu_f(acc[mi][ni][r] + bias[col]));
        }
      }
  } else {  // U_RECON
    float* C = (float*)Cv;
    float local = 0.f;
#pragma unroll
    for (int mi = 0; mi < 4; ++mi)
#pragma unroll
      for (int r = 0; r < 4; ++r) {
        const int row = rowBase + waveM + mi * 16 + quad * 4 + r;
#pragma unroll
        for (int ni = 0; ni < 4; ++ni) {
          const int col = colBase + waveN + ni * 16 + l15;
          const float val = acc[mi][ni][r] + bias[col];
          const float d = val - X[(size_t)row * N + col];
          local += d * d;
          C[(size_t)row * N + col] = val;
        }
      }
#pragma unroll
    for (int o = 32; o > 0; o >>= 1) local += __shfl_down(local, o);
    __shared__ float psh[NW];
    if (lane == 0) psh[w] = local;
    __syncthreads();
    if (tid == 0) {
      float t = 0.f;
#pragma unroll
      for (int i = 0; i < NW; ++i) t += psh[i];
      psum[blockIdx.y * gridDim.x + blockIdx.x] = t;  // unique slot, no atomic
    }
  }
}

// ===========================================================================
// Stage-1 distance — R19 dist2z: CT codes x BR rows, multi-block/CU packing
// (R16/R17 recipe), with the iteration reordered so the stage DMA is covered
// by the register-only epilogue:
//   MFMA(t) -> fence+barrier A (bf reads retired everywhere)
//   issue stage(t+1) -> epi (min+shfl+wred) under the DMA
//   vmcnt(0)+lgkm fence + barrier B (wred visible, bufB(t+1) landed)
//   merge + cand store
//   z: <256,64,64,64> grid (8,64)  = 512 blocks  = 2 blocks/CU (LDS 66K)
//   q: <128,64,64,16> grid (32,32) = 1024 blocks = 4 blocks/CU (LDS 33K)
// ===========================================================================
template <int KT, int CT, int BR, int BTG>
__global__ __launch_bounds__(256) void dist2z_kernel(
    const u16* __restrict__ CB, const u16* __restrict__ ZB,
    const float* __restrict__ cbn, u32* __restrict__ cand, int strideB,
    int ncand) {
  constexpr int CH = KT / 8;               // 16B-chunks per row
  constexpr int KSTEPS = KT / 32;
  constexpr int CSLOTS = (CT * CH) / 256;
  constexpr int BSLOTS = (BR * CH) / 256;
  __shared__ __align__(16) u16 bufC[CT * KT];  // codebook, persistent
  __shared__ __align__(16) u16 bufB[BR * KT];  // batch tile
  __shared__ u32 wred[BR * 2];
  const int tid = threadIdx.x;
  const int lane = tid & 63, w = tid >> 6;
  const int quad = lane >> 4, l15 = lane & 15;
  const int waveM = (w & 1) * 32;   // code half (32 codes)
  const int waveN = (w >> 1) * 32;  // batch half (32 rows)
  const int ct = blockIdx.y;
  const int btg = blockIdx.x;
  const int codeBase = ct * CT;

  float cnf[2][4];
#pragma unroll
  for (int mi = 0; mi < 2; ++mi)
#pragma unroll
    for (int r = 0; r < 4; ++r)
      cnf[mi][r] =
          cbn[codeBase + waveM + mi * 16 + quad * 4 + r] * 512.0f + 131072.0f;
  asm volatile("" ::: "memory");

  // ---- stage codebook -> bufC, batch tile 0 -> bufB ----
#pragma unroll
  for (int i = 0; i < CSLOTS; ++i) {
    const int ch = i * 256 + tid;
    const int r = ch / CH, c = ch % CH, g = c ^ (r & 7);
    load_lds16(CB + (size_t)(codeBase + r) * KT + g * 8, (char*)bufC + ch * 16);
  }
  {
    const int rowBase0 = btg * BTG * BR;
#pragma unroll
    for (int i = 0; i < BSLOTS; ++i) {
      const int ch = i * 256 + tid;
      const int r = ch / CH, c = ch % CH, g = c ^ (r & 7);
      load_lds16(ZB + (size_t)(rowBase0 + r) * strideB + g * 8,
                 (char*)bufB + ch * 16);
    }
  }
  wait_vmcnt<0>();
  barrier_raw();

  // ---- hoist A fragments; bufC never written again ----
  bf16x8 af[KSTEPS][2];
#pragma unroll
  for (int kk = 0; kk < KSTEPS; ++kk)
#pragma unroll
    for (int mi = 0; mi < 2; ++mi) {
      const int rl = waveM + mi * 16 + l15;
      const int sw = (kk * 4 + quad) ^ (rl & 7);
      af[kk][mi] = *(const bf16x8*)(bufC + rl * KT + sw * 8);
    }

#pragma unroll 1
  for (int bt = 0; bt < BTG; ++bt) {
    const int rowBase = (btg * BTG + bt) * BR;

    // ---- MFMA over bufB(bt) ----
    f32x4 acc[2][2] = {};
#pragma unroll
    for (int kk = 0; kk < KSTEPS; ++kk) {
      bf16x8 bf[2];
#pragma unroll
      for (int ni = 0; ni < 2; ++ni) {
        const int rn = waveN + ni * 16 + l15;
        const int sw = (kk * 4 + quad) ^ (rn & 7);
        bf[ni] = *(const bf16x8*)(bufB + rn * KT + sw * 8);
      }
#pragma unroll
      for (int mi = 0; mi < 2; ++mi)
#pragma unroll
        for (int ni = 0; ni < 2; ++ni)
          acc[mi][ni] = __builtin_amdgcn_mfma_f32_16x16x32_bf16(
              af[kk][mi], bf[ni], acc[mi][ni], 0, 0, 0);
    }
    // ---- barrier A: all waves' bufB reads retired -> DMA may overwrite ----
    lds_fence_barrier_pre();

    // ---- issue next tile's staging FIRST (DMA runs under the epilogue) ----
    if (bt + 1 < BTG) {
      const int rowBaseN = rowBase + BR;
#pragma unroll
      for (int i = 0; i < BSLOTS; ++i) {
        const int ch = i * 256 + tid;
        const int r = ch / CH, c = ch % CH, g = c ^ (r & 7);
        load_lds16(ZB + (size_t)(rowBaseN + r) * strideB + g * 8,
                   (char*)bufB + ch * 16);
      }
    }

    // ---- epilogue under the DMA: top-1 per row over this wave's 32 codes --
#pragma unroll
    for (int ni = 0; ni < 2; ++ni) {
      u32 b0 = ~0u;
#pragma unroll
      for (int mi = 0; mi < 2; ++mi)
#pragma unroll
        for (int r = 0; r < 4; ++r) {
          const float kf = fmaf(acc[mi][ni][r], -1024.0f, cnf[mi][r]);
          u32 iv = (u32)kf;
          iv = iv > 0xFFFFFu ? 0xFFFFFu : iv;
          const u32 key =
              (iv << 12) | (codeBase + waveM + mi * 16 + quad * 4 + r);
          b0 = min(b0, key);
        }
      b0 = min(b0, (u32)__shfl_xor(b0, 16));
      b0 = min(b0, (u32)__shfl_xor(b0, 32));
      if (quad == 0) {
        const int rloc = waveN + ni * 16 + l15;
        wred[rloc * 2 + (w & 1)] = b0;
      }
    }

    // ---- barrier B: wred visible + bufB(t+1) landed everywhere ----
    full_fence_barrier();

    // ---- merge + store (reads wred(bt); retire before next iter's A) ----
    if (tid < BR) {
      const u32 m0 = min(wred[tid * 2 + 0], wred[tid * 2 + 1]);
      cand[(size_t)(rowBase + tid) * ncand + ct] = m0;
    }
  }
}

// ===========================================================================
// Stage-2 rerank — R13/R17 (unchanged).
// ===========================================================================
template <int K, int NC, int LEVEL>
__global__ __launch_bounds__(256, 4) void rerank_kernel(
    const u32* __restrict__ cand, const u16* __restrict__ zes,
    const float* __restrict__ cb, const float* __restrict__ cbn,
    float* __restrict__ outq, u16* __restrict__ wsq,
    float* __restrict__ out_idx, float* __restrict__ psum) {
  constexpr int DV = K / 32;  // float4-chunks per lane dot slice (8 z / 4 q)
  constexpr int MV = K / 64;  // MSE elems per lane (4 z / 2 q)
  const int w = threadIdx.x >> 6, lane = threadIdx.x & 63;
  const int row = blockIdx.x * 4 + w;
  const int g = lane >> 3, sub = lane & 7;

  const u16* zr = zes + (size_t)row * 2 * K;

  // ---- phase 1: batch-issue all row-dependent loads ----
  ushort4 zh[DV], zl[DV];
#pragma unroll
  for (int i = 0; i < DV; ++i) {
    zh[i] = *(const ushort4*)(zr + sub * (K / 8) + 4 * i);
    zl[i] = *(const ushort4*)(zr + K + sub * (K / 8) + 4 * i);
  }
  float zmse[MV];
#pragma unroll
  for (int i = 0; i < MV; ++i) {
    const int c = lane + 64 * i;
    zmse[i] = bf16_to_f(zr[c]) + bf16_to_f(zr[K + c]);
  }
  const u32 mykey = (lane < NC) ? cand[(size_t)row * NC + lane] : ~0u;

  // ---- phase 2: top-8 by rank (LDS broadcast) ----
  __shared__ u32 kb[4][72];
  kb[w][lane] = mykey;
  __syncthreads();
  int rank = 0;
#pragma unroll
  for (int j = 0; j < 64; ++j) {
    const u32 kj = kb[w][j];
    rank += (kj < mykey || (kj == mykey && j < lane)) ? 1 : 0;
  }
  if (rank < 8) kb[w][64 + rank] = mykey;
  __syncthreads();
  const unsigned ci = kb[w][64 + g] & 0xFFFu;

  // ---- phase 3: exact f32 dot for this group's candidate ----
  const float* cr = cb + (size_t)ci * K;
  float dot = 0.f;
#pragma unroll
  for (int i = 0; i < DV; ++i) {
    const float4 cv = *(const float4*)(cr + sub * (K / 8) + 4 * i);
    dot = fmaf(bf16_to_f(zh[i].x) + bf16_to_f(zl[i].x), cv.x, dot);
    dot = fmaf(bf16_to_f(zh[i].y) + bf16_to_f(zl[i].y), cv.y, dot);
    dot = fmaf(bf16_to_f(zh[i].z) + bf16_to_f(zl[i].z), cv.z, dot);
    dot = fmaf(bf16_to_f(zh[i].w) + bf16_to_f(zl[i].w), cv.w, dot);
  }
#pragma unroll
  for (int off = 1; off < 8; off <<= 1) dot += __shfl_xor(dot, off);
  u64 k2 = pack_key(cbn[ci] - 2.0f * dot, ci);
#pragma unroll
  for (int off = 8; off < 64; off <<= 1) k2 = min64(k2, __shfl_xor(k2, off));
  const unsigned best = (unsigned)k2;
  if (lane == 0) out_idx[row] = (float)best;

  // ---- phase 4: gather best row, MSE + writes ----
  const float* br = cb + (size_t)best * K;
  float local = 0.f;
#pragma unroll
  for (int i = 0; i < MV; ++i) {
    const int c = lane + 64 * i;
    const float v = br[c];
    const float d = zmse[i] - v;
    local += d * d;
    outq[(size_t)row * K + c] = v;
    if (LEVEL == 0) {
      const u16 h = bf16_rne(v);
      wsq[(size_t)row * 2 * K + c] = h;
      wsq[(size_t)row * 2 * K + K + c] = bf16_rne(v - bf16_to_f(h));
    } else {
      wsq[(size_t)row * K + c] = bf16_rne(v);
    }
  }
#pragma unroll
  for (int o = 32; o > 0; o >>= 1) local += __shfl_down(local, o);
  __shared__ float p[4];
  if (lane == 0) p[w] = local;
  __syncthreads();
  if (threadIdx.x == 0) psum[blockIdx.x] = p[0] + p[1] + p[2] + p[3];
}

// ===========================================================================
// Finalize: sum the per-block partials (8192 z + 8192 q + 1024 recon).
// ===========================================================================
__global__ void finalize_kernel(const float* __restrict__ psumZ,
                                const float* __restrict__ psumQ,
                                const float* __restrict__ psumR,
                                float* __restrict__ out) {
  const int tid = threadIdx.x;
  float sz = 0.f, sq = 0.f, sr = 0.f;
  for (int i = tid; i < 8192; i += 256) {
    sz += psumZ[i];
    sq += psumQ[i];
  }
  for (int i = tid; i < 1024; i += 256) sr += psumR[i];
#pragma unroll
  for (int o = 32; o > 0; o >>= 1) {
    sz += __shfl_down(sz, o);
    sq += __shfl_down(sq, o);
    sr += __shfl_down(sr, o);
  }
  __shared__ float pz[4], pq[4], pr[4];
  if ((tid & 63) == 0) {
    pz[tid >> 6] = sz;
    pq[tid >> 6] = sq;
    pr[tid >> 6] = sr;
  }
  __syncthreads();
  if (tid == 0) {
    const float cz = (pz[0] + pz[1] + pz[2] + pz[3]) / ((float)kBatch * 256.f);
    const float cq = (pq[0] + pq[1] + pq[2] + pq[3]) / ((float)kBatch * 128.f);
    const float rec = (pr[0] + pr[1] + pr[2] + pr[3]) / ((float)kBatch * 512.f);
    out[0] = rec + 0.5f * cz + 0.5f * cq;
    out[1] = rec;
    out[2] = cz;
    out[3] = cz;
    out[4] = cq;
    out[5] = cq;
  }
}

}  // namespace

extern "C" void kernel_launch(void* const* d_in, const int* in_sizes, int n_in,
                              void* d_out, int out_size, void* d_ws,
                              size_t ws_size, hipStream_t stream) {
  const float* x   = (const float*)d_in[0];
  const float* eW1 = (const float*)d_in[1];
  const float* eb1 = (const float*)d_in[2];
  const float* eW2 = (const float*)d_in[3];
  const float* eb2 = (const float*)d_in[4];
  const float* zW  = (const float*)d_in[5];
  const float* zb  = (const float*)d_in[6];
  const float* zci = (const float*)d_in[7];
  const float* zcb = (const float*)d_in[8];
  const float* qW  = (const float*)d_in[9];
  const float* qb  = (const float*)d_in[10];
  const float* qci = (const float*)d_in[11];
  const float* qcb = (const float*)d_in[12];
  const float* dW1 = (const float*)d_in[13];
  const float* db1 = (const float*)d_in[14];
  const float* dW2 = (const float*)d_in[15];
  const float* db2 = (const float*)d_in[16];
  const float* oW  = (const float*)d_in[17];
  const float* ob  = (const float*)d_in[18];

  float* out = (float*)d_out;
  float* out_xr = out + 6;
  float* out_zq = out_xr + (size_t)32768 * 512;
  float* out_qq = out_zq + (size_t)32768 * 256;
  float* out_zi = out_qq + (size_t)32768 * 128;
  float* out_qi = out_zi + 32768;

  // ---- workspace layout ---------------------------------------------------
  char* wsb = (char*)d_ws;
  u16*  zWns = (u16*) (wsb + 0x0000000);  // 256 x 1536  768K
  u16*  qWns = (u16*) (wsb + 0x00C0000);  // 128 x 768   192K
  u16*  eW1s = (u16*) (wsb + 0x00F0000);  // 64 x 1536   192K
  u16*  eW2s = (u16*) (wsb + 0x0120000);  // 512 x 192   192K
  u16*  dW1b = (u16*) (wsb + 0x0150000);  // 64x128       16K
  u16*  dW2b = (u16*) (wsb + 0x0154000);  // 512x64       64K
  u16*  oWb  = (u16*) (wsb + 0x0164000);  // 512x512     512K
  u16*  zcbh = (u16*) (wsb + 0x01E4000);  // 4096x256      2M
  u16*  qcbh = (u16*) (wsb + 0x03E4000);  // 2048x128    512K
  float* zcbn = (float*)(wsb + 0x0464000); // 16K
  float* qcbn = (float*)(wsb + 0x0468000); // 8K
  float* psumR = (float*)(wsb + 0x046B000); // 1024 f32 = 4K
  float* psumZ = (float*)(wsb + 0x0470000); // 8192 f32 = 32K
  float* psumQ = (float*)(wsb + 0x0478000); // 8192 f32 = 32K
  // time-windowed regions:
  u16*  h1s  = (u16*) (wsb + 0x0480000);  // 8M  [enc1 -> enc2]
  u16*  h1b  = (u16*) (wsb + 0x0480000);  //   4M [dec1 -> dec2]
  u16*  zes  = (u16*) (wsb + 0x0C80000);  // 32M [zproj -> zdist,zrerank]
  u16*  qes  = (u16*) (wsb + 0x0C80000);  //   16M [qproj -> qdist,qrerank]
  u16*  hb   = (u16*) (wsb + 0x0C80000);  //   32M [dec2 -> recon]
  u16*  xs   = (u16*) (wsb + 0x2C80000);  // 64M [cast -> enc1]
  u16*  hs   = (u16*) (wsb + 0x2C80000);  //   64M [enc2 -> zproj]
  u32*  candz = (u32*)(wsb + 0x2C80000);  //   8M [zdist -> zrerank]
  u16*  zqs  = (u16*) (wsb + 0x3480000);  //   32M [zrerank -> qproj]
  u32*  candq = (u32*)(wsb + 0x2C80000);  //   4M [qdist -> qrerank]
  u16*  qqb  = (u16*) (wsb + 0x5480000);  //   8M [qrerank -> dec1]

  // ---- prep (3 launches; no memset needed — partials are plain stores) ----
  prep_cb_kernel<<<1536, 256, 0, stream>>>(zcb, zcbh, zcbn, qcb, qcbh, qcbn);
  prep_w_kernel<<<1824, 256, 0, stream>>>(zW, zci, qW, qci, eW1, eW2, zWns,
                                          qWns, eW1s, eW2s, dW1, dW2, oW,
                                          dW1b, dW2b, oWb);
  cast_split_x_kernel<<<16384, 256, 0, stream>>>(x, xs);

  // ---- encoder ----
  gemm_uni<128, 64, 2, U_GELU_SPLIT><<<dim3(1, 256), 128, 0, stream>>>(
      xs, eW1s, eb1, h1s, nullptr, nullptr, 1536, 1024, 1024, 64);
  gemm_uni<128, 128, 4, U_GELU_SPLIT><<<dim3(4, 256), 256, 0, stream>>>(
      h1s, eW2s, eb2, hs, nullptr, nullptr, 192, 128, 128, 512);
  gemm_uni<128, 128, 4, U_SIG_SPLIT><<<dim3(2, 256), 256, 0, stream>>>(
      hs, zWns, zb, zes, nullptr, nullptr, 1536, 1024, 1024, 256);

  // ---- z quantize: dist2z 64x64 tiles, grid (8,64) = 512 blocks = 2/CU
  dist2z_kernel<256, 64, 64, 64><<<dim3(8, 64), 256, 0, stream>>>(
      zcbh, zes, zcbn, candz, 512, 64);
  rerank_kernel<256, 64, 0><<<8192, 256, 0, stream>>>(
      candz, zes, zcb, zcbn, out_zq, zqs, out_zi, psumZ);

  // ---- q level: dist2z 64x64 tiles, grid (32,32) = 1024 blocks = 4/CU ----
  gemm_uni<128, 128, 4, U_SIG_SPLIT><<<dim3(1, 256), 256, 0, stream>>>(
      zqs, qWns, qb, qes, nullptr, nullptr, 768, 512, 512, 128);
  dist2z_kernel<128, 64, 64, 16><<<dim3(32, 32), 256, 0, stream>>>(
      qcbh, qes, qcbn, candq, 256, 32);
  rerank_kernel<128, 32, 1><<<8192, 256, 0, stream>>>(
      candq, qes, qcb, qcbn, out_qq, qqb, out_qi, psumQ);

  // ---- decoder ----
  gemm_uni<128, 64, 2, U_GELU_B16><<<dim3(1, 256), 128, 0, stream>>>(
      qqb, dW1b, db1, h1b, nullptr, nullptr, 128, 1 << 30, 128, 64);
  gemm_uni<128, 128, 4, U_GELU_B16><<<dim3(4, 256), 256, 0, stream>>>(
      h1b, dW2b, db2, hb, nullptr, nullptr, 64, 1 << 30, 64, 512);
  gemm_uni<128, 128, 4, U_RECON><<<dim3(4, 256), 256, 0, stream>>>(
      hb, oWb, ob, out_xr, x, psumR, 512, 1 << 30, 512, 512);

  finalize_kernel<<<1, 256, 0, stream>>>(psumZ, psumQ, psumR, out);

  (void)in_sizes; (void)n_in; (void)out_size; (void)ws_size;
}

// Round 12
// 675.821 us; speedup vs baseline: 1.0407x; 1.0382x over previous
//
#include <hip/hip_runtime.h>

typedef unsigned long long u64;
typedef unsigned short u16;
typedef unsigned int u32;

// ---------------------------------------------------------------------------
// HierarchicalLFQHVQVAE forward — R20.
// Base = R17 (667 us; R18/R19 regressed and are reverted).
// Dist ledger: the ONLY mechanism that moved z-dist is more independent
// blocks/CU (R16: 1->2 = -11us; q-dist at 4/CU runs ~25us). R18 proved
// staging traffic scales as 4096/CT -> never shrink codes/block.
// R20: z-dist -> dist4z<256,64,32,64>: CT=64 kept, batch tile halved to
// BR=32. LDS 32K+16K+0.25K = 48.3K -> 3 blocks/CU (145K); acc[2][1] ->
// VGPR < 88 -> 12 waves/CU = 3 waves/SIMD. Grid (16,64)=1024 blocks,
// lin%8=btg%8 -> 2 row-windows + codebook per XCD (~4MB L2). Iteration
// order = R17's proven (epi -> fence -> stage -> merge under DMA ->
// vmcnt(1) -> fence). cand layout [row*64+ct] unchanged -> rerank intact.
// q-dist (dist2z<128,64,64,16>, 4/CU), reranks, GEMMs, prep = R17.
// ---------------------------------------------------------------------------

namespace {

constexpr int kBatch = 32768;

__device__ __forceinline__ float gelu_f(float x) {
  return 0.5f * x * (1.0f + erff(x * 0.70710678118654752440f));
}
__device__ __forceinline__ float sigmoid_f(float x) {
  return 1.0f / (1.0f + expf(-x));
}
__device__ __forceinline__ u64 pack_key(float d, unsigned j) {
  unsigned u = __float_as_uint(d);
  u = (u & 0x80000000u) ? ~u : (u | 0x80000000u);
  return ((u64)u << 32) | j;
}
__device__ __forceinline__ u16 bf16_rne(float x) {
  unsigned u = __float_as_uint(x);
  unsigned r = (u + 0x7FFFu + ((u >> 16) & 1u)) >> 16;
  return (u16)r;
}
__device__ __forceinline__ float bf16_to_f(u16 h) {
  return __uint_as_float((unsigned)h << 16);
}
__device__ __forceinline__ u64 min64(u64 a, u64 b) { return a < b ? a : b; }

__device__ __forceinline__ void load_lds16(const void* g, void* l) {
  __builtin_amdgcn_global_load_lds(
      (const __attribute__((address_space(1))) void*)g,
      (__attribute__((address_space(3))) void*)l, 16, 0, 0);
}

template <int N>
__device__ __forceinline__ void wait_vmcnt() {
  if constexpr (N == 0) {
    asm volatile("s_waitcnt vmcnt(0)" ::: "memory");
  } else if constexpr (N == 1) {
    asm volatile("s_waitcnt vmcnt(1)" ::: "memory");
  } else if constexpr (N == 8) {
    asm volatile("s_waitcnt vmcnt(8)" ::: "memory");
  } else if constexpr (N == 16) {
    asm volatile("s_waitcnt vmcnt(16)" ::: "memory");
  }
}

__device__ __forceinline__ void lds_fence_barrier_pre() {
  // order: all prior LDS ops retired, then barrier
  asm volatile("s_waitcnt lgkmcnt(0)" ::: "memory");
  __builtin_amdgcn_sched_barrier(0);
  __builtin_amdgcn_s_barrier();
  asm volatile("" ::: "memory");  // no LDS op hoists above the barrier
  __builtin_amdgcn_sched_barrier(0);
}

__device__ __forceinline__ void barrier_raw() {
  __builtin_amdgcn_sched_barrier(0);
  __builtin_amdgcn_s_barrier();
  asm volatile("" ::: "memory");  // no LDS op hoists above the barrier
  __builtin_amdgcn_sched_barrier(0);
}

typedef short bf16x8 __attribute__((ext_vector_type(8)));
typedef float f32x4 __attribute__((ext_vector_type(4)));

// ===========================================================================
// Prep (3 kernels) — identical to R6
// ===========================================================================
__global__ void prep_cb_kernel(const float* __restrict__ zcb,
                               u16* __restrict__ zcbh, float* __restrict__ zcbn,
                               const float* __restrict__ qcb,
                               u16* __restrict__ qcbh, float* __restrict__ qcbn) {
  int b = blockIdx.x;
  const float* cb;
  u16* cbh;
  float* cbn;
  int K;
  if (b < 1024) { cb = zcb; cbh = zcbh; cbn = zcbn; K = 256; }
  else { b -= 1024; cb = qcb; cbh = qcbh; cbn = qcbn; K = 128; }
  const int row = b * 4 + (threadIdx.x >> 6);
  const int lane = threadIdx.x & 63;
  double s = 0.0;
  for (int k = lane; k < K; k += 64) {
    const float v = cb[(size_t)row * K + k];
    cbh[(size_t)row * K + k] = bf16_rne(v);
    s += (double)v * (double)v;
  }
#pragma unroll
  for (int o = 32; o > 0; o >>= 1) s += __shfl_down(s, o);
  if (lane == 0) cbn[row] = (float)s;
}

__global__ void prep_w_kernel(
    const float* __restrict__ zW, const float* __restrict__ zci,
    const float* __restrict__ qW, const float* __restrict__ qci,
    const float* __restrict__ eW1, const float* __restrict__ eW2,
    u16* __restrict__ zWns, u16* __restrict__ qWns, u16* __restrict__ eW1s,
    u16* __restrict__ eW2s, const float* __restrict__ dW1,
    const float* __restrict__ dW2, const float* __restrict__ oW,
    u16* __restrict__ dW1b, u16* __restrict__ dW2b, u16* __restrict__ oWb) {
  const int b = blockIdx.x;
  const int tid = threadIdx.x;
  if (b < 384) {
    const float* W;
    const float* ci;
    u16* D;
    int K, row;
    if (b < 256) { W = zW; ci = zci; D = zWns; K = 512; row = b; }
    else { W = qW; ci = qci; D = qWns; K = 256; row = b - 256; }
    float s = 0.f;
    for (int k = tid; k < K; k += 256) s += fabsf(W[(size_t)row * K + k]);
#pragma unroll
    for (int o = 32; o > 0; o >>= 1) s += __shfl_down(s, o);
    __shared__ float p[4];
    if ((tid & 63) == 0) p[tid >> 6] = s;
    __syncthreads();
    const float tot = p[0] + p[1] + p[2] + p[3];
    const float c = ci[row];
    const float sp = (c > 20.f) ? c : log1pf(expf(c));
    const float scale = fminf(1.f, sp / tot);
    for (int k = tid; k < K; k += 256) {
      const float v = W[(size_t)row * K + k] * scale;
      const u16 h = bf16_rne(v);
      const u16 l = bf16_rne(v - bf16_to_f(h));
      D[(size_t)row * 3 * K + k] = h;
      D[(size_t)row * 3 * K + K + k] = h;
      D[(size_t)row * 3 * K + 2 * K + k] = l;
    }
  } else if (b < 512) {  // eW1 split3, 64x512
    const int i = (b - 384) * 256 + tid;
    const int r = i >> 9, k = i & 511;
    const float v = eW1[i];
    const u16 h = bf16_rne(v);
    const u16 l = bf16_rne(v - bf16_to_f(h));
    eW1s[(size_t)r * 1536 + k] = h;
    eW1s[(size_t)r * 1536 + 512 + k] = h;
    eW1s[(size_t)r * 1536 + 1024 + k] = l;
  } else if (b < 640) {  // eW2 split3, 512x64
    const int i = (b - 512) * 256 + tid;
    const int r = i >> 6, k = i & 63;
    const float v = eW2[i];
    const u16 h = bf16_rne(v);
    const u16 l = bf16_rne(v - bf16_to_f(h));
    eW2s[(size_t)r * 192 + k] = h;
    eW2s[(size_t)r * 192 + 64 + k] = h;
    eW2s[(size_t)r * 192 + 128 + k] = l;
  } else if (b < 672) {
    const int i = (b - 640) * 256 + tid;
    dW1b[i] = bf16_rne(dW1[i]);
  } else if (b < 800) {
    const int i = (b - 672) * 256 + tid;
    dW2b[i] = bf16_rne(dW2[i]);
  } else {
    const int i = (b - 800) * 256 + tid;
    oWb[i] = bf16_rne(oW[i]);
  }
}

__global__ void cast_split_x_kernel(const float* __restrict__ x,
                                    u16* __restrict__ xs) {
  const int i = blockIdx.x * 256 + threadIdx.x;
  const int row = i >> 7, c4 = i & 127;
  const float4 v = *(const float4*)(x + (size_t)row * 512 + c4 * 4);
  const float vv[4] = {v.x, v.y, v.z, v.w};
  u16 hv[4], lv[4];
#pragma unroll
  for (int j = 0; j < 4; ++j) {
    hv[j] = bf16_rne(vv[j]);
    lv[j] = bf16_rne(vv[j] - bf16_to_f(hv[j]));
  }
  *(ushort4*)(xs + (size_t)row * 1024 + c4 * 4) =
      make_ushort4(hv[0], hv[1], hv[2], hv[3]);
  *(ushort4*)(xs + (size_t)row * 1024 + 512 + c4 * 4) =
      make_ushort4(lv[0], lv[1], lv[2], lv[3]);
}

// ===========================================================================
// Unified MFMA GEMM (identical to R13).
// ===========================================================================
enum { U_GELU_SPLIT = 0, U_SIG_SPLIT = 1, U_GELU_B16 = 2, U_RECON = 3 };

template <int TM, int TN, int NW, int MODE>
__global__ __launch_bounds__(NW * 64) void gemm_uni(
    const u16* __restrict__ A, const u16* __restrict__ B,
    const float* __restrict__ bias, void* __restrict__ Cv,
    const float* __restrict__ X, float* __restrict__ psum, int Ktot,
    int wrapA, int strideA, int N) {
  __shared__ __align__(16) u16 As[TM * 64];
  __shared__ __align__(16) u16 Bs[TN * 64];
  constexpr int NT = NW * 64;
  constexpr int AIT = (TM * 8) / NT;
  constexpr int BIT = (TN * 8) / NT;
  const int tid = threadIdx.x;
  const int lane = tid & 63, w = tid >> 6;
  const int quad = lane >> 4, l15 = lane & 15;
  const int waveM = (TN == 64) ? w * 64 : (w & 1) * 64;
  const int waveN = (TN == 64) ? 0 : (w >> 1) * 64;
  const int rowBase = blockIdx.y * TM;
  const int colBase = blockIdx.x * TN;

  f32x4 acc[4][4] = {};

  for (int k0 = 0; k0 < Ktot; k0 += 64) {
    const int sk0 = (k0 >= wrapA) ? k0 - wrapA : k0;
    __syncthreads();
#pragma unroll
    for (int i = 0; i < AIT; ++i) {
      const int ch = i * NT + tid;
      const int r = ch >> 3, c = ch & 7, g = c ^ (r & 7);
      load_lds16(A + (size_t)(rowBase + r) * strideA + sk0 + g * 8,
                 (char*)As + ch * 16);
    }
#pragma unroll
    for (int i = 0; i < BIT; ++i) {
      const int ch = i * NT + tid;
      const int r = ch >> 3, c = ch & 7, g = c ^ (r & 7);
      load_lds16(B + (size_t)(colBase + r) * Ktot + k0 + g * 8,
                 (char*)Bs + ch * 16);
    }
    __syncthreads();
#pragma unroll
    for (int ks = 0; ks < 2; ++ks) {
      bf16x8 af[4], bf[4];
      const int ch = ks * 4 + quad;
#pragma unroll
      for (int mi = 0; mi < 4; ++mi) {
        const int rl = waveM + mi * 16 + l15;
        af[mi] = *(const bf16x8*)(As + rl * 64 + (ch ^ (rl & 7)) * 8);
      }
#pragma unroll
      for (int ni = 0; ni < 4; ++ni) {
        const int rl = waveN + ni * 16 + l15;
        bf[ni] = *(const bf16x8*)(Bs + rl * 64 + (ch ^ (rl & 7)) * 8);
      }
#pragma unroll
      for (int mi = 0; mi < 4; ++mi)
#pragma unroll
        for (int ni = 0; ni < 4; ++ni)
          acc[mi][ni] = __builtin_amdgcn_mfma_f32_16x16x32_bf16(
              af[mi], bf[ni], acc[mi][ni], 0, 0, 0);
    }
  }

  if constexpr (MODE == U_GELU_SPLIT || MODE == U_SIG_SPLIT) {
    u16* S = (u16*)Cv;
#pragma unroll
    for (int mi = 0; mi < 4; ++mi)
#pragma unroll
      for (int r = 0; r < 4; ++r) {
        const int row = rowBase + waveM + mi * 16 + quad * 4 + r;
#pragma unroll
        for (int ni = 0; ni < 4; ++ni) {
          const int col = colBase + waveN + ni * 16 + l15;
          const float pre = acc[mi][ni][r] + bias[col];
          const float v = (MODE == U_GELU_SPLIT) ? gelu_f(pre) : sigmoid_f(pre);
          const u16 h = bf16_rne(v);
          const u16 l = bf16_rne(v - bf16_to_f(h));
          S[(size_t)row * 2 * N + col] = h;
          S[(size_t)row * 2 * N + N + col] = l;
        }
      }
  } else if constexpr (MODE == U_GELU_B16) {
    u16* C = (u16*)Cv;
#pragma unroll
    for (int mi = 0; mi < 4; ++mi)
#pragma unroll
      for (int r = 0; r < 4; ++r) {
        const int row = rowBase + waveM + mi * 16 + quad * 4 + r;
#pragma unroll
        for (int ni = 0; ni < 4; ++ni) {
          const int col = colBase + waveN + ni * 16 + l15;
          C[(size_t)row * N + col] =
              bf16_rne(gelu_f(acc[mi][ni][r] + bias[col]));
        }
      }
  } else {  // U_RECON
    float* C = (float*)Cv;
    float local = 0.f;
#pragma unroll
    for (int mi = 0; mi < 4; ++mi)
#pragma unroll
      for (int r = 0; r < 4; ++r) {
        const int row = rowBase + waveM + mi * 16 + quad * 4 + r;
#pragma unroll
        for (int ni = 0; ni < 4; ++ni) {
          const int col = colBase + waveN + ni * 16 + l15;
          const float val = acc[mi][ni][r] + bias[col];
          const float d = val - X[(size_t)row * N + col];
          local += d * d;
          C[(size_t)row * N + col] = val;
        }
      }
#pragma unroll
    for (int o = 32; o > 0; o >>= 1) local += __shfl_down(local, o);
    __shared__ float psh[NW];
    if (lane == 0) psh[w] = local;
    __syncthreads();
    if (tid == 0) {
      float t = 0.f;
#pragma unroll
      for (int i = 0; i < NW; ++i) t += psh[i];
      psum[blockIdx.y * gridDim.x + blockIdx.x] = t;  // unique slot, no atomic
    }
  }
}

// ===========================================================================
// z-level stage-1 distance — R20 dist4z: CT=64 codes x BR=32 rows,
// 3 blocks/CU (LDS 48.3K, VGPR <88). 4 waves = 2 code-halves x 2 row-halves
// (16 rows each), acc[2][1]. af[8][2] hoist kept. R17 iteration order:
// MFMA -> epi -> fence -> stage(t+1) -> merge under DMA -> vmcnt(1) -> fence.
// cand[row*64 + ct] (ncand=64) — rerank-compatible.
// ===========================================================================
template <int KT, int CT, int BR, int BTG>
__global__ __launch_bounds__(256) void dist4z_kernel(
    const u16* __restrict__ CB, const u16* __restrict__ ZB,
    const float* __restrict__ cbn, u32* __restrict__ cand, int strideB,
    int ncand) {
  constexpr int CH = KT / 8;               // 32 chunks/row
  constexpr int KSTEPS = KT / 32;          // 8
  constexpr int CSLOTS = (CT * CH) / 256;  // 8
  constexpr int BSLOTS = (BR * CH) / 256;  // 4
  __shared__ __align__(16) u16 bufC[CT * KT];  // 32KB codebook, persistent
  __shared__ __align__(16) u16 bufB[BR * KT];  // 16KB batch tile
  __shared__ u32 wred[BR * 2];
  const int tid = threadIdx.x;
  const int lane = tid & 63, w = tid >> 6;
  const int quad = lane >> 4, l15 = lane & 15;
  const int waveM = (w & 1) * 32;   // code half (32 codes)
  const int waveN = (w >> 1) * 16;  // row half (16 rows)
  const int ct = blockIdx.y;
  const int btg = blockIdx.x;
  const int codeBase = ct * CT;

  float cnf[2][4];
#pragma unroll
  for (int mi = 0; mi < 2; ++mi)
#pragma unroll
    for (int r = 0; r < 4; ++r)
      cnf[mi][r] =
          cbn[codeBase + waveM + mi * 16 + quad * 4 + r] * 512.0f + 131072.0f;
  asm volatile("" ::: "memory");

  // ---- stage codebook -> bufC, batch tile 0 -> bufB ----
#pragma unroll
  for (int i = 0; i < CSLOTS; ++i) {
    const int ch = i * 256 + tid;
    const int r = ch / CH, c = ch % CH, g = c ^ (r & 7);
    load_lds16(CB + (size_t)(codeBase + r) * KT + g * 8, (char*)bufC + ch * 16);
  }
  {
    const int rowBase0 = btg * BTG * BR;
#pragma unroll
    for (int i = 0; i < BSLOTS; ++i) {
      const int ch = i * 256 + tid;
      const int r = ch / CH, c = ch % CH, g = c ^ (r & 7);
      load_lds16(ZB + (size_t)(rowBase0 + r) * strideB + g * 8,
                 (char*)bufB + ch * 16);
    }
  }
  wait_vmcnt<0>();
  barrier_raw();

  // ---- hoist A fragments; bufC never written again ----
  bf16x8 af[KSTEPS][2];
#pragma unroll
  for (int kk = 0; kk < KSTEPS; ++kk)
#pragma unroll
    for (int mi = 0; mi < 2; ++mi) {
      const int rl = waveM + mi * 16 + l15;
      const int sw = (kk * 4 + quad) ^ (rl & 7);
      af[kk][mi] = *(const bf16x8*)(bufC + rl * KT + sw * 8);
    }

#pragma unroll 1
  for (int bt = 0; bt < BTG; ++bt) {
    const int rowBase = (btg * BTG + bt) * BR;

    // ---- MFMA over this wave's 16 rows x its 32 codes ----
    f32x4 acc[2] = {};
#pragma unroll
    for (int kk = 0; kk < KSTEPS; ++kk) {
      bf16x8 bf;
      {
        const int rn = waveN + l15;
        const int sw = (kk * 4 + quad) ^ (rn & 7);
        bf = *(const bf16x8*)(bufB + rn * KT + sw * 8);
      }
#pragma unroll
      for (int mi = 0; mi < 2; ++mi)
        acc[mi] = __builtin_amdgcn_mfma_f32_16x16x32_bf16(
            af[kk][mi], bf, acc[mi], 0, 0, 0);
    }

    // ---- epilogue: top-1 per row over this wave's 32 codes ----
    {
      u32 b0 = ~0u;
#pragma unroll
      for (int mi = 0; mi < 2; ++mi)
#pragma unroll
        for (int r = 0; r < 4; ++r) {
          const float kf = fmaf(acc[mi][r], -1024.0f, cnf[mi][r]);
          u32 iv = (u32)kf;
          iv = iv > 0xFFFFFu ? 0xFFFFFu : iv;
          const u32 key =
              (iv << 12) | (codeBase + waveM + mi * 16 + quad * 4 + r);
          b0 = min(b0, key);
        }
      b0 = min(b0, (u32)__shfl_xor(b0, 16));
      b0 = min(b0, (u32)__shfl_xor(b0, 32));
      if (quad == 0) {
        const int rloc = waveN + l15;
        wred[rloc * 2 + (w & 1)] = b0;
      }
    }
    // bufB reads + wred writes retired, then barrier
    lds_fence_barrier_pre();

    // ---- issue next tile's staging (DMA runs under the merge) ----
    if (bt + 1 < BTG) {
      const int rowBaseN = rowBase + BR;
#pragma unroll
      for (int i = 0; i < BSLOTS; ++i) {
        const int ch = i * 256 + tid;
        const int r = ch / CH, c = ch % CH, g = c ^ (r & 7);
        load_lds16(ZB + (size_t)(rowBaseN + r) * strideB + g * 8,
                   (char*)bufB + ch * 16);
      }
    }
    // ---- merge + store (reads wred(bt), safe vs stage: different region) --
    if (tid < BR) {
      const u32 m0 = min(wred[tid * 2 + 0], wred[tid * 2 + 1]);
      cand[(size_t)(rowBase + tid) * ncand + ct] = m0;
    }
    wait_vmcnt<1>();          // stages drained (cand store stays in flight)
    lds_fence_barrier_pre();  // visible to all; merge reads drained
  }
}

// ===========================================================================
// q-level stage-1 distance — R17 dist2z (unchanged): 64 codes x 64 rows,
// 4 blocks/CU. Top-1 per tile -> cand[row*32+ct].
// ===========================================================================
template <int KT, int CT, int BR, int BTG>
__global__ __launch_bounds__(256) void dist2z_kernel(
    const u16* __restrict__ CB, const u16* __restrict__ ZB,
    const float* __restrict__ cbn, u32* __restrict__ cand, int strideB,
    int ncand) {
  constexpr int CH = KT / 8;               // 16B-chunks per row
  constexpr int KSTEPS = KT / 32;
  constexpr int CSLOTS = (CT * CH) / 256;
  constexpr int BSLOTS = (BR * CH) / 256;
  __shared__ __align__(16) u16 bufC[CT * KT];  // codebook, persistent
  __shared__ __align__(16) u16 bufB[BR * KT];  // batch tile
  __shared__ u32 wred[BR * 2];
  const int tid = threadIdx.x;
  const int lane = tid & 63, w = tid >> 6;
  const int quad = lane >> 4, l15 = lane & 15;
  const int waveM = (w & 1) * 32;   // code half (32 codes)
  const int waveN = (w >> 1) * 32;  // batch half (32 rows)
  const int ct = blockIdx.y;
  const int btg = blockIdx.x;
  const int codeBase = ct * CT;

  float cnf[2][4];
#pragma unroll
  for (int mi = 0; mi < 2; ++mi)
#pragma unroll
    for (int r = 0; r < 4; ++r)
      cnf[mi][r] =
          cbn[codeBase + waveM + mi * 16 + quad * 4 + r] * 512.0f + 131072.0f;
  asm volatile("" ::: "memory");

  // ---- stage codebook -> bufC, batch tile 0 -> bufB ----
#pragma unroll
  for (int i = 0; i < CSLOTS; ++i) {
    const int ch = i * 256 + tid;
    const int r = ch / CH, c = ch % CH, g = c ^ (r & 7);
    load_lds16(CB + (size_t)(codeBase + r) * KT + g * 8, (char*)bufC + ch * 16);
  }
  {
    const int rowBase0 = btg * BTG * BR;
#pragma unroll
    for (int i = 0; i < BSLOTS; ++i) {
      const int ch = i * 256 + tid;
      const int r = ch / CH, c = ch % CH, g = c ^ (r & 7);
      load_lds16(ZB + (size_t)(rowBase0 + r) * strideB + g * 8,
                 (char*)bufB + ch * 16);
    }
  }
  wait_vmcnt<0>();
  barrier_raw();

  // ---- hoist A fragments; bufC never written again ----
  bf16x8 af[KSTEPS][2];
#pragma unroll
  for (int kk = 0; kk < KSTEPS; ++kk)
#pragma unroll
    for (int mi = 0; mi < 2; ++mi) {
      const int rl = waveM + mi * 16 + l15;
      const int sw = (kk * 4 + quad) ^ (rl & 7);
      af[kk][mi] = *(const bf16x8*)(bufC + rl * KT + sw * 8);
    }

#pragma unroll 1
  for (int bt = 0; bt < BTG; ++bt) {
    const int rowBase = (btg * BTG + bt) * BR;

    // ---- MFMA over bufB(bt) ----
    f32x4 acc[2][2] = {};
#pragma unroll
    for (int kk = 0; kk < KSTEPS; ++kk) {
      bf16x8 bf[2];
#pragma unroll
      for (int ni = 0; ni < 2; ++ni) {
        const int rn = waveN + ni * 16 + l15;
        const int sw = (kk * 4 + quad) ^ (rn & 7);
        bf[ni] = *(const bf16x8*)(bufB + rn * KT + sw * 8);
      }
#pragma unroll
      for (int mi = 0; mi < 2; ++mi)
#pragma unroll
        for (int ni = 0; ni < 2; ++ni)
          acc[mi][ni] = __builtin_amdgcn_mfma_f32_16x16x32_bf16(
              af[kk][mi], bf[ni], acc[mi][ni], 0, 0, 0);
    }

    // ---- epilogue: top-1 per batch row over this wave's 32 codes ----
#pragma unroll
    for (int ni = 0; ni < 2; ++ni) {
      u32 b0 = ~0u;
#pragma unroll
      for (int mi = 0; mi < 2; ++mi)
#pragma unroll
        for (int r = 0; r < 4; ++r) {
          const float kf = fmaf(acc[mi][ni][r], -1024.0f, cnf[mi][r]);
          u32 iv = (u32)kf;
          iv = iv > 0xFFFFFu ? 0xFFFFFu : iv;
          const u32 key =
              (iv << 12) | (codeBase + waveM + mi * 16 + quad * 4 + r);
          b0 = min(b0, key);
        }
      b0 = min(b0, (u32)__shfl_xor(b0, 16));
      b0 = min(b0, (u32)__shfl_xor(b0, 32));
      if (quad == 0) {
        const int rloc = waveN + ni * 16 + l15;
        wred[rloc * 2 + (w & 1)] = b0;
      }
    }
    // bufB reads + wred writes retired, then barrier
    lds_fence_barrier_pre();

    // ---- issue next tile's staging (DMA runs under the merge) ----
    if (bt + 1 < BTG) {
      const int rowBaseN = rowBase + BR;
#pragma unroll
      for (int i = 0; i < BSLOTS; ++i) {
        const int ch = i * 256 + tid;
        const int r = ch / CH, c = ch % CH, g = c ^ (r & 7);
        load_lds16(ZB + (size_t)(rowBaseN + r) * strideB + g * 8,
                   (char*)bufB + ch * 16);
      }
    }
    // ---- merge + store (reads wred(bt), safe vs stage: different region) --
    if (tid < BR) {
      const u32 m0 = min(wred[tid * 2 + 0], wred[tid * 2 + 1]);
      cand[(size_t)(rowBase + tid) * ncand + ct] = m0;
    }
    wait_vmcnt<1>();          // stages drained (cand store stays in flight)
    lds_fence_barrier_pre();  // visible to all; merge reads drained
  }
}

// ===========================================================================
// Stage-2 rerank — R13/R17 (unchanged).
// ===========================================================================
template <int K, int NC, int LEVEL>
__global__ __launch_bounds__(256, 4) void rerank_kernel(
    const u32* __restrict__ cand, const u16* __restrict__ zes,
    const float* __restrict__ cb, const float* __restrict__ cbn,
    float* __restrict__ outq, u16* __restrict__ wsq,
    float* __restrict__ out_idx, float* __restrict__ psum) {
  constexpr int DV = K / 32;  // float4-chunks per lane dot slice (8 z / 4 q)
  constexpr int MV = K / 64;  // MSE elems per lane (4 z / 2 q)
  const int w = threadIdx.x >> 6, lane = threadIdx.x & 63;
  const int row = blockIdx.x * 4 + w;
  const int g = lane >> 3, sub = lane & 7;

  const u16* zr = zes + (size_t)row * 2 * K;

  // ---- phase 1: batch-issue all row-dependent loads ----
  ushort4 zh[DV], zl[DV];
#pragma unroll
  for (int i = 0; i < DV; ++i) {
    zh[i] = *(const ushort4*)(zr + sub * (K / 8) + 4 * i);
    zl[i] = *(const ushort4*)(zr + K + sub * (K / 8) + 4 * i);
  }
  float zmse[MV];
#pragma unroll
  for (int i = 0; i < MV; ++i) {
    const int c = lane + 64 * i;
    zmse[i] = bf16_to_f(zr[c]) + bf16_to_f(zr[K + c]);
  }
  const u32 mykey = (lane < NC) ? cand[(size_t)row * NC + lane] : ~0u;

  // ---- phase 2: top-8 by rank (LDS broadcast) ----
  __shared__ u32 kb[4][72];
  kb[w][lane] = mykey;
  __syncthreads();
  int rank = 0;
#pragma unroll
  for (int j = 0; j < 64; ++j) {
    const u32 kj = kb[w][j];
    rank += (kj < mykey || (kj == mykey && j < lane)) ? 1 : 0;
  }
  if (rank < 8) kb[w][64 + rank] = mykey;
  __syncthreads();
  const unsigned ci = kb[w][64 + g] & 0xFFFu;

  // ---- phase 3: exact f32 dot for this group's candidate ----
  const float* cr = cb + (size_t)ci * K;
  float dot = 0.f;
#pragma unroll
  for (int i = 0; i < DV; ++i) {
    const float4 cv = *(const float4*)(cr + sub * (K / 8) + 4 * i);
    dot = fmaf(bf16_to_f(zh[i].x) + bf16_to_f(zl[i].x), cv.x, dot);
    dot = fmaf(bf16_to_f(zh[i].y) + bf16_to_f(zl[i].y), cv.y, dot);
    dot = fmaf(bf16_to_f(zh[i].z) + bf16_to_f(zl[i].z), cv.z, dot);
    dot = fmaf(bf16_to_f(zh[i].w) + bf16_to_f(zl[i].w), cv.w, dot);
  }
#pragma unroll
  for (int off = 1; off < 8; off <<= 1) dot += __shfl_xor(dot, off);
  u64 k2 = pack_key(cbn[ci] - 2.0f * dot, ci);
#pragma unroll
  for (int off = 8; off < 64; off <<= 1) k2 = min64(k2, __shfl_xor(k2, off));
  const unsigned best = (unsigned)k2;
  if (lane == 0) out_idx[row] = (float)best;

  // ---- phase 4: gather best row, MSE + writes ----
  const float* br = cb + (size_t)best * K;
  float local = 0.f;
#pragma unroll
  for (int i = 0; i < MV; ++i) {
    const int c = lane + 64 * i;
    const float v = br[c];
    const float d = zmse[i] - v;
    local += d * d;
    outq[(size_t)row * K + c] = v;
    if (LEVEL == 0) {
      const u16 h = bf16_rne(v);
      wsq[(size_t)row * 2 * K + c] = h;
      wsq[(size_t)row * 2 * K + K + c] = bf16_rne(v - bf16_to_f(h));
    } else {
      wsq[(size_t)row * K + c] = bf16_rne(v);
    }
  }
#pragma unroll
  for (int o = 32; o > 0; o >>= 1) local += __shfl_down(local, o);
  __shared__ float p[4];
  if (lane == 0) p[w] = local;
  __syncthreads();
  if (threadIdx.x == 0) psum[blockIdx.x] = p[0] + p[1] + p[2] + p[3];
}

// ===========================================================================
// Finalize: sum the per-block partials (8192 z + 8192 q + 1024 recon).
// ===========================================================================
__global__ void finalize_kernel(const float* __restrict__ psumZ,
                                const float* __restrict__ psumQ,
                                const float* __restrict__ psumR,
                                float* __restrict__ out) {
  const int tid = threadIdx.x;
  float sz = 0.f, sq = 0.f, sr = 0.f;
  for (int i = tid; i < 8192; i += 256) {
    sz += psumZ[i];
    sq += psumQ[i];
  }
  for (int i = tid; i < 1024; i += 256) sr += psumR[i];
#pragma unroll
  for (int o = 32; o > 0; o >>= 1) {
    sz += __shfl_down(sz, o);
    sq += __shfl_down(sq, o);
    sr += __shfl_down(sr, o);
  }
  __shared__ float pz[4], pq[4], pr[4];
  if ((tid & 63) == 0) {
    pz[tid >> 6] = sz;
    pq[tid >> 6] = sq;
    pr[tid >> 6] = sr;
  }
  __syncthreads();
  if (tid == 0) {
    const float cz = (pz[0] + pz[1] + pz[2] + pz[3]) / ((float)kBatch * 256.f);
    const float cq = (pq[0] + pq[1] + pq[2] + pq[3]) / ((float)kBatch * 128.f);
    const float rec = (pr[0] + pr[1] + pr[2] + pr[3]) / ((float)kBatch * 512.f);
    out[0] = rec + 0.5f * cz + 0.5f * cq;
    out[1] = rec;
    out[2] = cz;
    out[3] = cz;
    out[4] = cq;
    out[5] = cq;
  }
}

}  // namespace

extern "C" void kernel_launch(void* const* d_in, const int* in_sizes, int n_in,
                              void* d_out, int out_size, void* d_ws,
                              size_t ws_size, hipStream_t stream) {
  const float* x   = (const float*)d_in[0];
  const float* eW1 = (const float*)d_in[1];
  const float* eb1 = (const float*)d_in[2];
  const float* eW2 = (const float*)d_in[3];
  const float* eb2 = (const float*)d_in[4];
  const float* zW  = (const float*)d_in[5];
  const float* zb  = (const float*)d_in[6];
  const float* zci = (const float*)d_in[7];
  const float* zcb = (const float*)d_in[8];
  const float* qW  = (const float*)d_in[9];
  const float* qb  = (const float*)d_in[10];
  const float* qci = (const float*)d_in[11];
  const float* qcb = (const float*)d_in[12];
  const float* dW1 = (const float*)d_in[13];
  const float* db1 = (const float*)d_in[14];
  const float* dW2 = (const float*)d_in[15];
  const float* db2 = (const float*)d_in[16];
  const float* oW  = (const float*)d_in[17];
  const float* ob  = (const float*)d_in[18];

  float* out = (float*)d_out;
  float* out_xr = out + 6;
  float* out_zq = out_xr + (size_t)32768 * 512;
  float* out_qq = out_zq + (size_t)32768 * 256;
  float* out_zi = out_qq + (size_t)32768 * 128;
  float* out_qi = out_zi + 32768;

  // ---- workspace layout ---------------------------------------------------
  char* wsb = (char*)d_ws;
  u16*  zWns = (u16*) (wsb + 0x0000000);  // 256 x 1536  768K
  u16*  qWns = (u16*) (wsb + 0x00C0000);  // 128 x 768   192K
  u16*  eW1s = (u16*) (wsb + 0x00F0000);  // 64 x 1536   192K
  u16*  eW2s = (u16*) (wsb + 0x0120000);  // 512 x 192   192K
  u16*  dW1b = (u16*) (wsb + 0x0150000);  // 64x128       16K
  u16*  dW2b = (u16*) (wsb + 0x0154000);  // 512x64       64K
  u16*  oWb  = (u16*) (wsb + 0x0164000);  // 512x512     512K
  u16*  zcbh = (u16*) (wsb + 0x01E4000);  // 4096x256      2M
  u16*  qcbh = (u16*) (wsb + 0x03E4000);  // 2048x128    512K
  float* zcbn = (float*)(wsb + 0x0464000); // 16K
  float* qcbn = (float*)(wsb + 0x0468000); // 8K
  float* psumR = (float*)(wsb + 0x046B000); // 1024 f32 = 4K
  float* psumZ = (float*)(wsb + 0x0470000); // 8192 f32 = 32K
  float* psumQ = (float*)(wsb + 0x0478000); // 8192 f32 = 32K
  // time-windowed regions:
  u16*  h1s  = (u16*) (wsb + 0x0480000);  // 8M  [enc1 -> enc2]
  u16*  h1b  = (u16*) (wsb + 0x0480000);  //   4M [dec1 -> dec2]
  u16*  zes  = (u16*) (wsb + 0x0C80000);  // 32M [zproj -> zdist,zrerank]
  u16*  qes  = (u16*) (wsb + 0x0C80000);  //   16M [qproj -> qdist,qrerank]
  u16*  hb   = (u16*) (wsb + 0x0C80000);  //   32M [dec2 -> recon]
  u16*  xs   = (u16*) (wsb + 0x2C80000);  // 64M [cast -> enc1]
  u16*  hs   = (u16*) (wsb + 0x2C80000);  //   64M [enc2 -> zproj]
  u32*  candz = (u32*)(wsb + 0x2C80000);  //   8M [zdist -> zrerank]
  u16*  zqs  = (u16*) (wsb + 0x3480000);  //   32M [zrerank -> qproj]
  u32*  candq = (u32*)(wsb + 0x2C80000);  //   4M [qdist -> qrerank]
  u16*  qqb  = (u16*) (wsb + 0x5480000);  //   8M [qrerank -> dec1]

  // ---- prep (3 launches; no memset needed — partials are plain stores) ----
  prep_cb_kernel<<<1536, 256, 0, stream>>>(zcb, zcbh, zcbn, qcb, qcbh, qcbn);
  prep_w_kernel<<<1824, 256, 0, stream>>>(zW, zci, qW, qci, eW1, eW2, zWns,
                                          qWns, eW1s, eW2s, dW1, dW2, oW,
                                          dW1b, dW2b, oWb);
  cast_split_x_kernel<<<16384, 256, 0, stream>>>(x, xs);

  // ---- encoder ----
  gemm_uni<128, 64, 2, U_GELU_SPLIT><<<dim3(1, 256), 128, 0, stream>>>(
      xs, eW1s, eb1, h1s, nullptr, nullptr, 1536, 1024, 1024, 64);
  gemm_uni<128, 128, 4, U_GELU_SPLIT><<<dim3(4, 256), 256, 0, stream>>>(
      h1s, eW2s, eb2, hs, nullptr, nullptr, 192, 128, 128, 512);
  gemm_uni<128, 128, 4, U_SIG_SPLIT><<<dim3(2, 256), 256, 0, stream>>>(
      hs, zWns, zb, zes, nullptr, nullptr, 1536, 1024, 1024, 256);

  // ---- z quantize: dist4z 64x32 tiles, grid (16,64) = 1024 blocks = 3/CU
  //      (LDS 48.3K); top-1/tile -> cand[row*64+ct]
  dist4z_kernel<256, 64, 32, 64><<<dim3(16, 64), 256, 0, stream>>>(
      zcbh, zes, zcbn, candz, 512, 64);
  rerank_kernel<256, 64, 0><<<8192, 256, 0, stream>>>(
      candz, zes, zcb, zcbn, out_zq, zqs, out_zi, psumZ);

  // ---- q level: dist2z 64x64 tiles, grid (32,32) = 1024 blocks = 4/CU ----
  gemm_uni<128, 128, 4, U_SIG_SPLIT><<<dim3(1, 256), 256, 0, stream>>>(
      zqs, qWns, qb, qes, nullptr, nullptr, 768, 512, 512, 128);
  dist2z_kernel<128, 64, 64, 16><<<dim3(32, 32), 256, 0, stream>>>(
      qcbh, qes, qcbn, candq, 256, 32);
  rerank_kernel<128, 32, 1><<<8192, 256, 0, stream>>>(
      candq, qes, qcb, qcbn, out_qq, qqb, out_qi, psumQ);

  // ---- decoder ----
  gemm_uni<128, 64, 2, U_GELU_B16><<<dim3(1, 256), 128, 0, stream>>>(
      qqb, dW1b, db1, h1b, nullptr, nullptr, 128, 1 << 30, 128, 64);
  gemm_uni<128, 128, 4, U_GELU_B16><<<dim3(4, 256), 256, 0, stream>>>(
      h1b, dW2b, db2, hb, nullptr, nullptr, 64, 1 << 30, 64, 512);
  gemm_uni<128, 128, 4, U_RECON><<<dim3(4, 256), 256, 0, stream>>>(
      hb, oWb, ob, out_xr, x, psumR, 512, 1 << 30, 512, 512);

  finalize_kernel<<<1, 256, 0, stream>>>(psumZ, psumQ, psumR, out);

  (void)in_sizes; (void)n_in; (void)out_size; (void)ws_size;
}

// Round 13
// 666.464 us; speedup vs baseline: 1.0554x; 1.0140x over previous
//
#include <hip/hip_runtime.h>

typedef unsigned long long u64;
typedef unsigned short u16;
typedef unsigned int u32;

// ---------------------------------------------------------------------------
// HierarchicalLFQHVQVAE forward — R21.
// Base = R17 (667.4 us) — R18/R19/R20 all regressed and are fully reverted.
// Dist stage-1 ledger (8 experiments): dist2z<64,64> @ 2 blocks/CU (z) and
// 4 blocks/CU (q) is the local optimum; every perturbation (same-block
// waves R14, in-wave interleave R15, decomposition flip R18, reorder R19,
// smaller tiles R20) was null or negative. 630 TF ~ the 2-barrier
// small-tile structural ceiling at this shape.
// R21 = R17 + ONE cheap untried lever: s_setprio(1) around the MFMA phase
// in dist2z (T5). Catalog: T5 pays with phase-diverse waves (attn +4-7%,
// independent blocks) and is null in lockstep GEMM. dist2z matches the
// attn regime: 2-4 INDEPENDENT blocks/CU drift out of phase, so priority
// arbitration can favor compute-phase waves over co-resident staging waves.
// Everything else byte-identical to R17.
// ---------------------------------------------------------------------------

namespace {

constexpr int kBatch = 32768;

__device__ __forceinline__ float gelu_f(float x) {
  return 0.5f * x * (1.0f + erff(x * 0.70710678118654752440f));
}
__device__ __forceinline__ float sigmoid_f(float x) {
  return 1.0f / (1.0f + expf(-x));
}
__device__ __forceinline__ u64 pack_key(float d, unsigned j) {
  unsigned u = __float_as_uint(d);
  u = (u & 0x80000000u) ? ~u : (u | 0x80000000u);
  return ((u64)u << 32) | j;
}
__device__ __forceinline__ u16 bf16_rne(float x) {
  unsigned u = __float_as_uint(x);
  unsigned r = (u + 0x7FFFu + ((u >> 16) & 1u)) >> 16;
  return (u16)r;
}
__device__ __forceinline__ float bf16_to_f(u16 h) {
  return __uint_as_float((unsigned)h << 16);
}
__device__ __forceinline__ u64 min64(u64 a, u64 b) { return a < b ? a : b; }

__device__ __forceinline__ void load_lds16(const void* g, void* l) {
  __builtin_amdgcn_global_load_lds(
      (const __attribute__((address_space(1))) void*)g,
      (__attribute__((address_space(3))) void*)l, 16, 0, 0);
}

template <int N>
__device__ __forceinline__ void wait_vmcnt() {
  if constexpr (N == 0) {
    asm volatile("s_waitcnt vmcnt(0)" ::: "memory");
  } else if constexpr (N == 1) {
    asm volatile("s_waitcnt vmcnt(1)" ::: "memory");
  } else if constexpr (N == 8) {
    asm volatile("s_waitcnt vmcnt(8)" ::: "memory");
  } else if constexpr (N == 16) {
    asm volatile("s_waitcnt vmcnt(16)" ::: "memory");
  }
}

__device__ __forceinline__ void lds_fence_barrier_pre() {
  // order: all prior LDS ops retired, then barrier
  asm volatile("s_waitcnt lgkmcnt(0)" ::: "memory");
  __builtin_amdgcn_sched_barrier(0);
  __builtin_amdgcn_s_barrier();
  asm volatile("" ::: "memory");  // no LDS op hoists above the barrier
  __builtin_amdgcn_sched_barrier(0);
}

__device__ __forceinline__ void barrier_raw() {
  __builtin_amdgcn_sched_barrier(0);
  __builtin_amdgcn_s_barrier();
  asm volatile("" ::: "memory");  // no LDS op hoists above the barrier
  __builtin_amdgcn_sched_barrier(0);
}

typedef short bf16x8 __attribute__((ext_vector_type(8)));
typedef float f32x4 __attribute__((ext_vector_type(4)));

// ===========================================================================
// Prep (3 kernels) — identical to R6
// ===========================================================================
__global__ void prep_cb_kernel(const float* __restrict__ zcb,
                               u16* __restrict__ zcbh, float* __restrict__ zcbn,
                               const float* __restrict__ qcb,
                               u16* __restrict__ qcbh, float* __restrict__ qcbn) {
  int b = blockIdx.x;
  const float* cb;
  u16* cbh;
  float* cbn;
  int K;
  if (b < 1024) { cb = zcb; cbh = zcbh; cbn = zcbn; K = 256; }
  else { b -= 1024; cb = qcb; cbh = qcbh; cbn = qcbn; K = 128; }
  const int row = b * 4 + (threadIdx.x >> 6);
  const int lane = threadIdx.x & 63;
  double s = 0.0;
  for (int k = lane; k < K; k += 64) {
    const float v = cb[(size_t)row * K + k];
    cbh[(size_t)row * K + k] = bf16_rne(v);
    s += (double)v * (double)v;
  }
#pragma unroll
  for (int o = 32; o > 0; o >>= 1) s += __shfl_down(s, o);
  if (lane == 0) cbn[row] = (float)s;
}

__global__ void prep_w_kernel(
    const float* __restrict__ zW, const float* __restrict__ zci,
    const float* __restrict__ qW, const float* __restrict__ qci,
    const float* __restrict__ eW1, const float* __restrict__ eW2,
    u16* __restrict__ zWns, u16* __restrict__ qWns, u16* __restrict__ eW1s,
    u16* __restrict__ eW2s, const float* __restrict__ dW1,
    const float* __restrict__ dW2, const float* __restrict__ oW,
    u16* __restrict__ dW1b, u16* __restrict__ dW2b, u16* __restrict__ oWb) {
  const int b = blockIdx.x;
  const int tid = threadIdx.x;
  if (b < 384) {
    const float* W;
    const float* ci;
    u16* D;
    int K, row;
    if (b < 256) { W = zW; ci = zci; D = zWns; K = 512; row = b; }
    else { W = qW; ci = qci; D = qWns; K = 256; row = b - 256; }
    float s = 0.f;
    for (int k = tid; k < K; k += 256) s += fabsf(W[(size_t)row * K + k]);
#pragma unroll
    for (int o = 32; o > 0; o >>= 1) s += __shfl_down(s, o);
    __shared__ float p[4];
    if ((tid & 63) == 0) p[tid >> 6] = s;
    __syncthreads();
    const float tot = p[0] + p[1] + p[2] + p[3];
    const float c = ci[row];
    const float sp = (c > 20.f) ? c : log1pf(expf(c));
    const float scale = fminf(1.f, sp / tot);
    for (int k = tid; k < K; k += 256) {
      const float v = W[(size_t)row * K + k] * scale;
      const u16 h = bf16_rne(v);
      const u16 l = bf16_rne(v - bf16_to_f(h));
      D[(size_t)row * 3 * K + k] = h;
      D[(size_t)row * 3 * K + K + k] = h;
      D[(size_t)row * 3 * K + 2 * K + k] = l;
    }
  } else if (b < 512) {  // eW1 split3, 64x512
    const int i = (b - 384) * 256 + tid;
    const int r = i >> 9, k = i & 511;
    const float v = eW1[i];
    const u16 h = bf16_rne(v);
    const u16 l = bf16_rne(v - bf16_to_f(h));
    eW1s[(size_t)r * 1536 + k] = h;
    eW1s[(size_t)r * 1536 + 512 + k] = h;
    eW1s[(size_t)r * 1536 + 1024 + k] = l;
  } else if (b < 640) {  // eW2 split3, 512x64
    const int i = (b - 512) * 256 + tid;
    const int r = i >> 6, k = i & 63;
    const float v = eW2[i];
    const u16 h = bf16_rne(v);
    const u16 l = bf16_rne(v - bf16_to_f(h));
    eW2s[(size_t)r * 192 + k] = h;
    eW2s[(size_t)r * 192 + 64 + k] = h;
    eW2s[(size_t)r * 192 + 128 + k] = l;
  } else if (b < 672) {
    const int i = (b - 640) * 256 + tid;
    dW1b[i] = bf16_rne(dW1[i]);
  } else if (b < 800) {
    const int i = (b - 672) * 256 + tid;
    dW2b[i] = bf16_rne(dW2[i]);
  } else {
    const int i = (b - 800) * 256 + tid;
    oWb[i] = bf16_rne(oW[i]);
  }
}

__global__ void cast_split_x_kernel(const float* __restrict__ x,
                                    u16* __restrict__ xs) {
  const int i = blockIdx.x * 256 + threadIdx.x;
  const int row = i >> 7, c4 = i & 127;
  const float4 v = *(const float4*)(x + (size_t)row * 512 + c4 * 4);
  const float vv[4] = {v.x, v.y, v.z, v.w};
  u16 hv[4], lv[4];
#pragma unroll
  for (int j = 0; j < 4; ++j) {
    hv[j] = bf16_rne(vv[j]);
    lv[j] = bf16_rne(vv[j] - bf16_to_f(hv[j]));
  }
  *(ushort4*)(xs + (size_t)row * 1024 + c4 * 4) =
      make_ushort4(hv[0], hv[1], hv[2], hv[3]);
  *(ushort4*)(xs + (size_t)row * 1024 + 512 + c4 * 4) =
      make_ushort4(lv[0], lv[1], lv[2], lv[3]);
}

// ===========================================================================
// Unified MFMA GEMM (identical to R13).
// ===========================================================================
enum { U_GELU_SPLIT = 0, U_SIG_SPLIT = 1, U_GELU_B16 = 2, U_RECON = 3 };

template <int TM, int TN, int NW, int MODE>
__global__ __launch_bounds__(NW * 64) void gemm_uni(
    const u16* __restrict__ A, const u16* __restrict__ B,
    const float* __restrict__ bias, void* __restrict__ Cv,
    const float* __restrict__ X, float* __restrict__ psum, int Ktot,
    int wrapA, int strideA, int N) {
  __shared__ __align__(16) u16 As[TM * 64];
  __shared__ __align__(16) u16 Bs[TN * 64];
  constexpr int NT = NW * 64;
  constexpr int AIT = (TM * 8) / NT;
  constexpr int BIT = (TN * 8) / NT;
  const int tid = threadIdx.x;
  const int lane = tid & 63, w = tid >> 6;
  const int quad = lane >> 4, l15 = lane & 15;
  const int waveM = (TN == 64) ? w * 64 : (w & 1) * 64;
  const int waveN = (TN == 64) ? 0 : (w >> 1) * 64;
  const int rowBase = blockIdx.y * TM;
  const int colBase = blockIdx.x * TN;

  f32x4 acc[4][4] = {};

  for (int k0 = 0; k0 < Ktot; k0 += 64) {
    const int sk0 = (k0 >= wrapA) ? k0 - wrapA : k0;
    __syncthreads();
#pragma unroll
    for (int i = 0; i < AIT; ++i) {
      const int ch = i * NT + tid;
      const int r = ch >> 3, c = ch & 7, g = c ^ (r & 7);
      load_lds16(A + (size_t)(rowBase + r) * strideA + sk0 + g * 8,
                 (char*)As + ch * 16);
    }
#pragma unroll
    for (int i = 0; i < BIT; ++i) {
      const int ch = i * NT + tid;
      const int r = ch >> 3, c = ch & 7, g = c ^ (r & 7);
      load_lds16(B + (size_t)(colBase + r) * Ktot + k0 + g * 8,
                 (char*)Bs + ch * 16);
    }
    __syncthreads();
#pragma unroll
    for (int ks = 0; ks < 2; ++ks) {
      bf16x8 af[4], bf[4];
      const int ch = ks * 4 + quad;
#pragma unroll
      for (int mi = 0; mi < 4; ++mi) {
        const int rl = waveM + mi * 16 + l15;
        af[mi] = *(const bf16x8*)(As + rl * 64 + (ch ^ (rl & 7)) * 8);
      }
#pragma unroll
      for (int ni = 0; ni < 4; ++ni) {
        const int rl = waveN + ni * 16 + l15;
        bf[ni] = *(const bf16x8*)(Bs + rl * 64 + (ch ^ (rl & 7)) * 8);
      }
#pragma unroll
      for (int mi = 0; mi < 4; ++mi)
#pragma unroll
        for (int ni = 0; ni < 4; ++ni)
          acc[mi][ni] = __builtin_amdgcn_mfma_f32_16x16x32_bf16(
              af[mi], bf[ni], acc[mi][ni], 0, 0, 0);
    }
  }

  if constexpr (MODE == U_GELU_SPLIT || MODE == U_SIG_SPLIT) {
    u16* S = (u16*)Cv;
#pragma unroll
    for (int mi = 0; mi < 4; ++mi)
#pragma unroll
      for (int r = 0; r < 4; ++r) {
        const int row = rowBase + waveM + mi * 16 + quad * 4 + r;
#pragma unroll
        for (int ni = 0; ni < 4; ++ni) {
          const int col = colBase + waveN + ni * 16 + l15;
          const float pre = acc[mi][ni][r] + bias[col];
          const float v = (MODE == U_GELU_SPLIT) ? gelu_f(pre) : sigmoid_f(pre);
          const u16 h = bf16_rne(v);
          const u16 l = bf16_rne(v - bf16_to_f(h));
          S[(size_t)row * 2 * N + col] = h;
          S[(size_t)row * 2 * N + N + col] = l;
        }
      }
  } else if constexpr (MODE == U_GELU_B16) {
    u16* C = (u16*)Cv;
#pragma unroll
    for (int mi = 0; mi < 4; ++mi)
#pragma unroll
      for (int r = 0; r < 4; ++r) {
        const int row = rowBase + waveM + mi * 16 + quad * 4 + r;
#pragma unroll
        for (int ni = 0; ni < 4; ++ni) {
          const int col = colBase + waveN + ni * 16 + l15;
          C[(size_t)row * N + col] =
              bf16_rne(gelu_f(acc[mi][ni][r] + bias[col]));
        }
      }
  } else {  // U_RECON
    float* C = (float*)Cv;
    float local = 0.f;
#pragma unroll
    for (int mi = 0; mi < 4; ++mi)
#pragma unroll
      for (int r = 0; r < 4; ++r) {
        const int row = rowBase + waveM + mi * 16 + quad * 4 + r;
#pragma unroll
        for (int ni = 0; ni < 4; ++ni) {
          const int col = colBase + waveN + ni * 16 + l15;
          const float val = acc[mi][ni][r] + bias[col];
          const float d = val - X[(size_t)row * N + col];
          local += d * d;
          C[(size_t)row * N + col] = val;
        }
      }
#pragma unroll
    for (int o = 32; o > 0; o >>= 1) local += __shfl_down(local, o);
    __shared__ float psh[NW];
    if (lane == 0) psh[w] = local;
    __syncthreads();
    if (tid == 0) {
      float t = 0.f;
#pragma unroll
      for (int i = 0; i < NW; ++i) t += psh[i];
      psum[blockIdx.y * gridDim.x + blockIdx.x] = t;  // unique slot, no atomic
    }
  }
}

// ===========================================================================
// Stage-1 distance — R17 dist2z + T5 setprio around the MFMA phase.
//   z: <256,64,64,64> grid (8,64)  = 512 blocks  = 2 blocks/CU (LDS 66K)
//   q: <128,64,64,16> grid (32,32) = 1024 blocks = 4 blocks/CU (LDS 33K)
// bufC persistent + af hoist; bufB single-buffered. Top-1 per tile ->
// cand[row*ncand + ct]. Per iter: [setprio(1)] MFMA [setprio(0)] -> epi ->
// fence -> issue stage(t+1) -> merge under DMA -> vmcnt(1) -> fence.
// ===========================================================================
template <int KT, int CT, int BR, int BTG>
__global__ __launch_bounds__(256) void dist2z_kernel(
    const u16* __restrict__ CB, const u16* __restrict__ ZB,
    const float* __restrict__ cbn, u32* __restrict__ cand, int strideB,
    int ncand) {
  constexpr int CH = KT / 8;               // 16B-chunks per row
  constexpr int KSTEPS = KT / 32;
  constexpr int CSLOTS = (CT * CH) / 256;
  constexpr int BSLOTS = (BR * CH) / 256;
  __shared__ __align__(16) u16 bufC[CT * KT];  // codebook, persistent
  __shared__ __align__(16) u16 bufB[BR * KT];  // batch tile
  __shared__ u32 wred[BR * 2];
  const int tid = threadIdx.x;
  const int lane = tid & 63, w = tid >> 6;
  const int quad = lane >> 4, l15 = lane & 15;
  const int waveM = (w & 1) * 32;   // code half (32 codes)
  const int waveN = (w >> 1) * 32;  // batch half (32 rows)
  const int ct = blockIdx.y;
  const int btg = blockIdx.x;
  const int codeBase = ct * CT;

  float cnf[2][4];
#pragma unroll
  for (int mi = 0; mi < 2; ++mi)
#pragma unroll
    for (int r = 0; r < 4; ++r)
      cnf[mi][r] =
          cbn[codeBase + waveM + mi * 16 + quad * 4 + r] * 512.0f + 131072.0f;
  asm volatile("" ::: "memory");

  // ---- stage codebook -> bufC, batch tile 0 -> bufB ----
#pragma unroll
  for (int i = 0; i < CSLOTS; ++i) {
    const int ch = i * 256 + tid;
    const int r = ch / CH, c = ch % CH, g = c ^ (r & 7);
    load_lds16(CB + (size_t)(codeBase + r) * KT + g * 8, (char*)bufC + ch * 16);
  }
  {
    const int rowBase0 = btg * BTG * BR;
#pragma unroll
    for (int i = 0; i < BSLOTS; ++i) {
      const int ch = i * 256 + tid;
      const int r = ch / CH, c = ch % CH, g = c ^ (r & 7);
      load_lds16(ZB + (size_t)(rowBase0 + r) * strideB + g * 8,
                 (char*)bufB + ch * 16);
    }
  }
  wait_vmcnt<0>();
  barrier_raw();

  // ---- hoist A fragments; bufC never written again ----
  bf16x8 af[KSTEPS][2];
#pragma unroll
  for (int kk = 0; kk < KSTEPS; ++kk)
#pragma unroll
    for (int mi = 0; mi < 2; ++mi) {
      const int rl = waveM + mi * 16 + l15;
      const int sw = (kk * 4 + quad) ^ (rl & 7);
      af[kk][mi] = *(const bf16x8*)(bufC + rl * KT + sw * 8);
    }

#pragma unroll 1
  for (int bt = 0; bt < BTG; ++bt) {
    const int rowBase = (btg * BTG + bt) * BR;

    // ---- MFMA over bufB(bt) — T5: elevate priority for the compute phase
    __builtin_amdgcn_s_setprio(1);
    f32x4 acc[2][2] = {};
#pragma unroll
    for (int kk = 0; kk < KSTEPS; ++kk) {
      bf16x8 bf[2];
#pragma unroll
      for (int ni = 0; ni < 2; ++ni) {
        const int rn = waveN + ni * 16 + l15;
        const int sw = (kk * 4 + quad) ^ (rn & 7);
        bf[ni] = *(const bf16x8*)(bufB + rn * KT + sw * 8);
      }
#pragma unroll
      for (int mi = 0; mi < 2; ++mi)
#pragma unroll
        for (int ni = 0; ni < 2; ++ni)
          acc[mi][ni] = __builtin_amdgcn_mfma_f32_16x16x32_bf16(
              af[kk][mi], bf[ni], acc[mi][ni], 0, 0, 0);
    }
    __builtin_amdgcn_s_setprio(0);

    // ---- epilogue: top-1 per batch row over this wave's 32 codes ----
#pragma unroll
    for (int ni = 0; ni < 2; ++ni) {
      u32 b0 = ~0u;
#pragma unroll
      for (int mi = 0; mi < 2; ++mi)
#pragma unroll
        for (int r = 0; r < 4; ++r) {
          const float kf = fmaf(acc[mi][ni][r], -1024.0f, cnf[mi][r]);
          u32 iv = (u32)kf;
          iv = iv > 0xFFFFFu ? 0xFFFFFu : iv;
          const u32 key =
              (iv << 12) | (codeBase + waveM + mi * 16 + quad * 4 + r);
          b0 = min(b0, key);
        }
      b0 = min(b0, (u32)__shfl_xor(b0, 16));
      b0 = min(b0, (u32)__shfl_xor(b0, 32));
      if (quad == 0) {
        const int rloc = waveN + ni * 16 + l15;
        wred[rloc * 2 + (w & 1)] = b0;
      }
    }
    // bufB reads + wred writes retired, then barrier
    lds_fence_barrier_pre();

    // ---- issue next tile's staging (DMA runs under the merge) ----
    if (bt + 1 < BTG) {
      const int rowBaseN = rowBase + BR;
#pragma unroll
      for (int i = 0; i < BSLOTS; ++i) {
        const int ch = i * 256 + tid;
        const int r = ch / CH, c = ch % CH, g = c ^ (r & 7);
        load_lds16(ZB + (size_t)(rowBaseN + r) * strideB + g * 8,
                   (char*)bufB + ch * 16);
      }
    }
    // ---- merge + store (reads wred(bt), safe vs stage: different region) --
    if (tid < BR) {
      const u32 m0 = min(wred[tid * 2 + 0], wred[tid * 2 + 1]);
      cand[(size_t)(rowBase + tid) * ncand + ct] = m0;
    }
    wait_vmcnt<1>();          // stages drained (cand store stays in flight)
    lds_fence_barrier_pre();  // visible to all; merge reads drained
  }
}

// ===========================================================================
// Stage-2 rerank — R13/R17 (unchanged).
// ===========================================================================
template <int K, int NC, int LEVEL>
__global__ __launch_bounds__(256, 4) void rerank_kernel(
    const u32* __restrict__ cand, const u16* __restrict__ zes,
    const float* __restrict__ cb, const float* __restrict__ cbn,
    float* __restrict__ outq, u16* __restrict__ wsq,
    float* __restrict__ out_idx, float* __restrict__ psum) {
  constexpr int DV = K / 32;  // float4-chunks per lane dot slice (8 z / 4 q)
  constexpr int MV = K / 64;  // MSE elems per lane (4 z / 2 q)
  const int w = threadIdx.x >> 6, lane = threadIdx.x & 63;
  const int row = blockIdx.x * 4 + w;
  const int g = lane >> 3, sub = lane & 7;

  const u16* zr = zes + (size_t)row * 2 * K;

  // ---- phase 1: batch-issue all row-dependent loads ----
  ushort4 zh[DV], zl[DV];
#pragma unroll
  for (int i = 0; i < DV; ++i) {
    zh[i] = *(const ushort4*)(zr + sub * (K / 8) + 4 * i);
    zl[i] = *(const ushort4*)(zr + K + sub * (K / 8) + 4 * i);
  }
  float zmse[MV];
#pragma unroll
  for (int i = 0; i < MV; ++i) {
    const int c = lane + 64 * i;
    zmse[i] = bf16_to_f(zr[c]) + bf16_to_f(zr[K + c]);
  }
  const u32 mykey = (lane < NC) ? cand[(size_t)row * NC + lane] : ~0u;

  // ---- phase 2: top-8 by rank (LDS broadcast) ----
  __shared__ u32 kb[4][72];
  kb[w][lane] = mykey;
  __syncthreads();
  int rank = 0;
#pragma unroll
  for (int j = 0; j < 64; ++j) {
    const u32 kj = kb[w][j];
    rank += (kj < mykey || (kj == mykey && j < lane)) ? 1 : 0;
  }
  if (rank < 8) kb[w][64 + rank] = mykey;
  __syncthreads();
  const unsigned ci = kb[w][64 + g] & 0xFFFu;

  // ---- phase 3: exact f32 dot for this group's candidate ----
  const float* cr = cb + (size_t)ci * K;
  float dot = 0.f;
#pragma unroll
  for (int i = 0; i < DV; ++i) {
    const float4 cv = *(const float4*)(cr + sub * (K / 8) + 4 * i);
    dot = fmaf(bf16_to_f(zh[i].x) + bf16_to_f(zl[i].x), cv.x, dot);
    dot = fmaf(bf16_to_f(zh[i].y) + bf16_to_f(zl[i].y), cv.y, dot);
    dot = fmaf(bf16_to_f(zh[i].z) + bf16_to_f(zl[i].z), cv.z, dot);
    dot = fmaf(bf16_to_f(zh[i].w) + bf16_to_f(zl[i].w), cv.w, dot);
  }
#pragma unroll
  for (int off = 1; off < 8; off <<= 1) dot += __shfl_xor(dot, off);
  u64 k2 = pack_key(cbn[ci] - 2.0f * dot, ci);
#pragma unroll
  for (int off = 8; off < 64; off <<= 1) k2 = min64(k2, __shfl_xor(k2, off));
  const unsigned best = (unsigned)k2;
  if (lane == 0) out_idx[row] = (float)best;

  // ---- phase 4: gather best row, MSE + writes ----
  const float* br = cb + (size_t)best * K;
  float local = 0.f;
#pragma unroll
  for (int i = 0; i < MV; ++i) {
    const int c = lane + 64 * i;
    const float v = br[c];
    const float d = zmse[i] - v;
    local += d * d;
    outq[(size_t)row * K + c] = v;
    if (LEVEL == 0) {
      const u16 h = bf16_rne(v);
      wsq[(size_t)row * 2 * K + c] = h;
      wsq[(size_t)row * 2 * K + K + c] = bf16_rne(v - bf16_to_f(h));
    } else {
      wsq[(size_t)row * K + c] = bf16_rne(v);
    }
  }
#pragma unroll
  for (int o = 32; o > 0; o >>= 1) local += __shfl_down(local, o);
  __shared__ float p[4];
  if (lane == 0) p[w] = local;
  __syncthreads();
  if (threadIdx.x == 0) psum[blockIdx.x] = p[0] + p[1] + p[2] + p[3];
}

// ===========================================================================
// Finalize: sum the per-block partials (8192 z + 8192 q + 1024 recon).
// ===========================================================================
__global__ void finalize_kernel(const float* __restrict__ psumZ,
                                const float* __restrict__ psumQ,
                                const float* __restrict__ psumR,
                                float* __restrict__ out) {
  const int tid = threadIdx.x;
  float sz = 0.f, sq = 0.f, sr = 0.f;
  for (int i = tid; i < 8192; i += 256) {
    sz += psumZ[i];
    sq += psumQ[i];
  }
  for (int i = tid; i < 1024; i += 256) sr += psumR[i];
#pragma unroll
  for (int o = 32; o > 0; o >>= 1) {
    sz += __shfl_down(sz, o);
    sq += __shfl_down(sq, o);
    sr += __shfl_down(sr, o);
  }
  __shared__ float pz[4], pq[4], pr[4];
  if ((tid & 63) == 0) {
    pz[tid >> 6] = sz;
    pq[tid >> 6] = sq;
    pr[tid >> 6] = sr;
  }
  __syncthreads();
  if (tid == 0) {
    const float cz = (pz[0] + pz[1] + pz[2] + pz[3]) / ((float)kBatch * 256.f);
    const float cq = (pq[0] + pq[1] + pq[2] + pq[3]) / ((float)kBatch * 128.f);
    const float rec = (pr[0] + pr[1] + pr[2] + pr[3]) / ((float)kBatch * 512.f);
    out[0] = rec + 0.5f * cz + 0.5f * cq;
    out[1] = rec;
    out[2] = cz;
    out[3] = cz;
    out[4] = cq;
    out[5] = cq;
  }
}

}  // namespace

extern "C" void kernel_launch(void* const* d_in, const int* in_sizes, int n_in,
                              void* d_out, int out_size, void* d_ws,
                              size_t ws_size, hipStream_t stream) {
  const float* x   = (const float*)d_in[0];
  const float* eW1 = (const float*)d_in[1];
  const float* eb1 = (const float*)d_in[2];
  const float* eW2 = (const float*)d_in[3];
  const float* eb2 = (const float*)d_in[4];
  const float* zW  = (const float*)d_in[5];
  const float* zb  = (const float*)d_in[6];
  const float* zci = (const float*)d_in[7];
  const float* zcb = (const float*)d_in[8];
  const float* qW  = (const float*)d_in[9];
  const float* qb  = (const float*)d_in[10];
  const float* qci = (const float*)d_in[11];
  const float* qcb = (const float*)d_in[12];
  const float* dW1 = (const float*)d_in[13];
  const float* db1 = (const float*)d_in[14];
  const float* dW2 = (const float*)d_in[15];
  const float* db2 = (const float*)d_in[16];
  const float* oW  = (const float*)d_in[17];
  const float* ob  = (const float*)d_in[18];

  float* out = (float*)d_out;
  float* out_xr = out + 6;
  float* out_zq = out_xr + (size_t)32768 * 512;
  float* out_qq = out_zq + (size_t)32768 * 256;
  float* out_zi = out_qq + (size_t)32768 * 128;
  float* out_qi = out_zi + 32768;

  // ---- workspace layout ---------------------------------------------------
  char* wsb = (char*)d_ws;
  u16*  zWns = (u16*) (wsb + 0x0000000);  // 256 x 1536  768K
  u16*  qWns = (u16*) (wsb + 0x00C0000);  // 128 x 768   192K
  u16*  eW1s = (u16*) (wsb + 0x00F0000);  // 64 x 1536   192K
  u16*  eW2s = (u16*) (wsb + 0x0120000);  // 512 x 192   192K
  u16*  dW1b = (u16*) (wsb + 0x0150000);  // 64x128       16K
  u16*  dW2b = (u16*) (wsb + 0x0154000);  // 512x64       64K
  u16*  oWb  = (u16*) (wsb + 0x0164000);  // 512x512     512K
  u16*  zcbh = (u16*) (wsb + 0x01E4000);  // 4096x256      2M
  u16*  qcbh = (u16*) (wsb + 0x03E4000);  // 2048x128    512K
  float* zcbn = (float*)(wsb + 0x0464000); // 16K
  float* qcbn = (float*)(wsb + 0x0468000); // 8K
  float* psumR = (float*)(wsb + 0x046B000); // 1024 f32 = 4K
  float* psumZ = (float*)(wsb + 0x0470000); // 8192 f32 = 32K
  float* psumQ = (float*)(wsb + 0x0478000); // 8192 f32 = 32K
  // time-windowed regions:
  u16*  h1s  = (u16*) (wsb + 0x0480000);  // 8M  [enc1 -> enc2]
  u16*  h1b  = (u16*) (wsb + 0x0480000);  //   4M [dec1 -> dec2]
  u16*  zes  = (u16*) (wsb + 0x0C80000);  // 32M [zproj -> zdist,zrerank]
  u16*  qes  = (u16*) (wsb + 0x0C80000);  //   16M [qproj -> qdist,qrerank]
  u16*  hb   = (u16*) (wsb + 0x0C80000);  //   32M [dec2 -> recon]
  u16*  xs   = (u16*) (wsb + 0x2C80000);  // 64M [cast -> enc1]
  u16*  hs   = (u16*) (wsb + 0x2C80000);  //   64M [enc2 -> zproj]
  u32*  candz = (u32*)(wsb + 0x2C80000);  //   8M [zdist -> zrerank]
  u16*  zqs  = (u16*) (wsb + 0x3480000);  //   32M [zrerank -> qproj]
  u32*  candq = (u32*)(wsb + 0x2C80000);  //   4M [qdist -> qrerank]
  u16*  qqb  = (u16*) (wsb + 0x5480000);  //   8M [qrerank -> dec1]

  // ---- prep (3 launches; no memset needed — partials are plain stores) ----
  prep_cb_kernel<<<1536, 256, 0, stream>>>(zcb, zcbh, zcbn, qcb, qcbh, qcbn);
  prep_w_kernel<<<1824, 256, 0, stream>>>(zW, zci, qW, qci, eW1, eW2, zWns,
                                          qWns, eW1s, eW2s, dW1, dW2, oW,
                                          dW1b, dW2b, oWb);
  cast_split_x_kernel<<<16384, 256, 0, stream>>>(x, xs);

  // ---- encoder ----
  gemm_uni<128, 64, 2, U_GELU_SPLIT><<<dim3(1, 256), 128, 0, stream>>>(
      xs, eW1s, eb1, h1s, nullptr, nullptr, 1536, 1024, 1024, 64);
  gemm_uni<128, 128, 4, U_GELU_SPLIT><<<dim3(4, 256), 256, 0, stream>>>(
      h1s, eW2s, eb2, hs, nullptr, nullptr, 192, 128, 128, 512);
  gemm_uni<128, 128, 4, U_SIG_SPLIT><<<dim3(2, 256), 256, 0, stream>>>(
      hs, zWns, zb, zes, nullptr, nullptr, 1536, 1024, 1024, 256);

  // ---- z quantize: dist2z 64x64 tiles, grid (8,64) = 512 blocks = 2/CU
  dist2z_kernel<256, 64, 64, 64><<<dim3(8, 64), 256, 0, stream>>>(
      zcbh, zes, zcbn, candz, 512, 64);
  rerank_kernel<256, 64, 0><<<8192, 256, 0, stream>>>(
      candz, zes, zcb, zcbn, out_zq, zqs, out_zi, psumZ);

  // ---- q level: dist2z 64x64 tiles, grid (32,32) = 1024 blocks = 4/CU ----
  gemm_uni<128, 128, 4, U_SIG_SPLIT><<<dim3(1, 256), 256, 0, stream>>>(
      zqs, qWns, qb, qes, nullptr, nullptr, 768, 512, 512, 128);
  dist2z_kernel<128, 64, 64, 16><<<dim3(32, 32), 256, 0, stream>>>(
      qcbh, qes, qcbn, candq, 256, 32);
  rerank_kernel<128, 32, 1><<<8192, 256, 0, stream>>>(
      candq, qes, qcb, qcbn, out_qq, qqb, out_qi, psumQ);

  // ---- decoder ----
  gemm_uni<128, 64, 2, U_GELU_B16><<<dim3(1, 256), 128, 0, stream>>>(
      qqb, dW1b, db1, h1b, nullptr, nullptr, 128, 1 << 30, 128, 64);
  gemm_uni<128, 128, 4, U_GELU_B16><<<dim3(4, 256), 256, 0, stream>>>(
      h1b, dW2b, db2, hb, nullptr, nullptr, 64, 1 << 30, 64, 512);
  gemm_uni<128, 128, 4, U_RECON><<<dim3(4, 256), 256, 0, stream>>>(
      hb, oWb, ob, out_xr, x, psumR, 512, 1 << 30, 512, 512);

  finalize_kernel<<<1, 256, 0, stream>>>(psumZ, psumQ, psumR, out);

  (void)in_sizes; (void)n_in; (void)out_size; (void)ws_size;
}